// Round 23
// baseline (266.020 us; speedup 1.0000x reference)
//
#include <hip/hip_runtime.h>
#include <hip/hip_bf16.h>
#include <math.h>

#define HIDDEN   1024
#define HEADS    16
#define HEAD_DIM 64
#define BATCH    4
#define SEQ      4096
#define M_TOTAL  (BATCH * SEQ)          // 16384
#define FFT_N    4096
#define WSZ      ((size_t)HIDDEN * HIDDEN)
#define PI2      6.28318530717958647692f

typedef _Float16 f16x8 __attribute__((ext_vector_type(8)));   // 8 fp16 = 4 VGPR (MFMA A/B frag)
typedef float    f32x4 __attribute__((ext_vector_type(4)));   // MFMA C/D frag

#if defined(__has_builtin)
#if __has_builtin(__builtin_amdgcn_global_load_lds)
#define HAVE_GLL 1
#else
#define HAVE_GLL 0
#endif
#else
#define HAVE_GLL 0
#endif

#if HAVE_GLL
// async global->LDS, 16B/lane. dest = wave-uniform base + lane*16 (linear in slot).
__device__ __forceinline__ void gload16(const void* g, void* l) {
    __builtin_amdgcn_global_load_lds(
        (const __attribute__((address_space(1))) unsigned int*)g,
        (__attribute__((address_space(3))) unsigned int*)l,
        16, 0, 0);
}
#endif

__device__ __forceinline__ void cvt8_f16(float4 v0, float4 v1,
                                         ushort* __restrict__ d) {
    const float vv[8] = {v0.x, v0.y, v0.z, v0.w, v1.x, v1.y, v1.z, v1.w};
    f16x8 hv;
    #pragma unroll
    for (int e = 0; e < 8; ++e) hv[e] = (_Float16)vv[e];
    *(f16x8*)d = hv;
}

// ---------------------------------------------------------------------------
// Pre-pass kernels (r20/r22-validated)
// ---------------------------------------------------------------------------
__global__ __launch_bounds__(256) void cvt16_kernel(
    const float* __restrict__ src, ushort* __restrict__ h)
{
    const size_t i = ((size_t)blockIdx.x * 256 + threadIdx.x) * 8;
    float4 v0 = *(const float4*)(src + i);
    float4 v1 = *(const float4*)(src + i + 4);
    cvt8_f16(v0, v1, h + i);
}

__global__ __launch_bounds__(256) void cvtW_kernel(
    const float* __restrict__ Wq, const float* __restrict__ Wk,
    const float* __restrict__ Wv, const float* __restrict__ Wo,
    ushort* __restrict__ wh, ushort* __restrict__ woh)
{
    const int p = blockIdx.y;                 // 0=q 1=k 2=v 3=o
    const size_t i = ((size_t)blockIdx.x * 256 + threadIdx.x) * 8;
    const float* __restrict__ src = (p == 0) ? Wq : (p == 1 ? Wk : (p == 2 ? Wv : Wo));
    ushort* __restrict__ dst = (p < 3) ? (wh + (size_t)p * WSZ) : woh;
    float4 v0 = *(const float4*)(src + i);
    float4 v1 = *(const float4*)(src + i + 4);
    cvt8_f16(v0, v1, dst + i);
}

// ---------------------------------------------------------------------------
// QKV GEMM (r20/r22-VALIDATED, byte-identical)
// ---------------------------------------------------------------------------
__global__ __launch_bounds__(1024, 1) void gemm_qkv_mfma8(
    const ushort* __restrict__ xh, const ushort* __restrict__ wh,
    const float* __restrict__ bq, const float* __restrict__ bk,
    const float* __restrict__ bv,
    ushort* __restrict__ qkvt)
{
    __shared__ ushort Ah[3][8192];
    __shared__ ushort Bh[3][8192];

    const int tid  = threadIdx.x;
    const int lane = tid & 63;
    const int wid  = tid >> 6;
    const int wr   = wid >> 2;
    const int wc   = wid & 3;
    const int m0   = blockIdx.x * 256;
    const int ng0  = blockIdx.y * 256;
    const int p    = ng0 >> 10;
    const int n0p  = ng0 & 1023;

    const float* __restrict__ bias = (p == 0) ? bq : (p == 1 ? bk : bv);
    ushort* __restrict__ ct = qkvt + (size_t)p * HIDDEN * M_TOTAL;

    const int row = tid >> 2;
    const int chS = (tid & 3) ^ ((row >> 1) & 3);

    const int fr = lane & 15;
    const int fc = lane >> 4;
    const int cc = (fc ^ ((fr >> 1) & 3)) * 8;

    f32x4 acc[4][4];
    #pragma unroll
    for (int rf = 0; rf < 4; ++rf)
        #pragma unroll
        for (int cf = 0; cf < 4; ++cf)
            acc[rf][cf] = (f32x4){0.f, 0.f, 0.f, 0.f};

#if HAVE_GLL
    #define QKV_STAGE(K0, SLOT) {                                                  \
        const size_t gw = (size_t)(ng0 + row) * HIDDEN + (K0) + (size_t)chS * 8;   \
        const size_t gx = (size_t)(m0 + row) * HIDDEN + (K0) + (size_t)chS * 8;    \
        gload16(wh + gw, &Ah[SLOT][(size_t)tid * 8]);                              \
        gload16(xh + gx, &Bh[SLOT][(size_t)tid * 8]);                              \
    }
#else
    #define QKV_STAGE(K0, SLOT) {                                                  \
        const size_t gw = (size_t)(ng0 + row) * HIDDEN + (K0) + (size_t)chS * 8;   \
        const size_t gx = (size_t)(m0 + row) * HIDDEN + (K0) + (size_t)chS * 8;    \
        *(f16x8*)&Ah[SLOT][(size_t)tid * 8] = *(const f16x8*)(wh + gw);            \
        *(f16x8*)&Bh[SLOT][(size_t)tid * 8] = *(const f16x8*)(xh + gx);            \
    }
#endif

    QKV_STAGE(0, 0);
    QKV_STAGE(32, 1);

    for (int ks = 0; ks < 32; ++ks) {
        const int slot = ks % 3;
#if HAVE_GLL
        if (ks == 31) { asm volatile("s_waitcnt vmcnt(0)" ::: "memory"); }
        else          { asm volatile("s_waitcnt vmcnt(2)" ::: "memory"); }
        __builtin_amdgcn_s_barrier();
        asm volatile("" ::: "memory");
#else
        __syncthreads();
#endif
        {
            const ushort* pAh = Ah[slot];
            const ushort* pBh = Bh[slot];
            f16x8 a_h[4], b_h[4];
            #pragma unroll
            for (int rf = 0; rf < 4; ++rf) {
                const int R = wr * 64 + rf * 16 + fr;
                a_h[rf] = *(const f16x8*)(pAh + R * 32 + cc);
            }
            #pragma unroll
            for (int cf = 0; cf < 4; ++cf) {
                const int R = wc * 64 + cf * 16 + fr;
                b_h[cf] = *(const f16x8*)(pBh + R * 32 + cc);
            }
            #pragma unroll
            for (int rf = 0; rf < 4; ++rf)
                #pragma unroll
                for (int cf = 0; cf < 4; ++cf)
                    acc[rf][cf] = __builtin_amdgcn_mfma_f32_16x16x32_f16(a_h[rf], b_h[cf], acc[rf][cf], 0, 0, 0);
        }
        if (ks + 2 < 32) { QKV_STAGE((ks + 2) * 32, (ks + 2) % 3); }
#if !HAVE_GLL
        __syncthreads();
#endif
    }
    #undef QKV_STAGE

    const int rq = lane >> 4;
    #pragma unroll
    for (int rf = 0; rf < 4; ++rf) {
        #pragma unroll
        for (int r = 0; r < 4; ++r) {
            const int nl = wr * 64 + rf * 16 + rq * 4 + r;
            const float bv = bias[n0p + nl];
            ushort* dst = ct + (size_t)(n0p + nl) * M_TOTAL + m0 + wc * 64;
            #pragma unroll
            for (int cf = 0; cf < 4; ++cf) {
                union { _Float16 f; ushort u; } cvt;
                cvt.f = (_Float16)(acc[rf][cf][r] + bv);
                dst[cf * 16 + fr] = cvt.u;
            }
        }
    }
}

// ---------------------------------------------------------------------------
// Radix-16 FFT, paired sequences (r22-VALIDATED math), 768-THREAD GROUPS:
// group g = tid>>8 owns buffer g (Z1, Z2, V12) -> the 3 independent forward
// FFTs run in PARALLEL (3 wall stage-units instead of 9). Pointwise splits
// over slices s = g + 3*it. Inverse (1 buffer, serially dependent stages)
// runs on group 0; groups 1,2 idle there. 12 waves/block x 2 blocks/CU =
// 24 waves/CU (was 8) -> latency hiding for the pack/unpack chains.
// All formulas byte-identical to r22; branches wave-uniform.
// ---------------------------------------------------------------------------
__device__ __forceinline__ float2 cmul(float2 a, float2 b) {
    return {a.x*b.x - a.y*b.y, a.x*b.y + a.y*b.x};
}

__device__ __forceinline__ int phys(int p) { return p ^ ((p >> 4) & 15); }

__device__ __forceinline__ unsigned pk16(float2 v) {
    union { _Float16 f[2]; unsigned u; } c;
    c.f[0] = (_Float16)v.x; c.f[1] = (_Float16)v.y;
    return c.u;
}
__device__ __forceinline__ float2 upk16(unsigned u) {
    union { unsigned uu; _Float16 f[2]; } c; c.uu = u;
    return (float2){(float)c.f[0], (float)c.f[1]};
}

template<int DIR>
__device__ __forceinline__ void dft16(const float2* x, float2* X) {
    float2 t[16];
    #pragma unroll
    for (int n0 = 0; n0 < 4; ++n0) {
        float2 a = x[n0], b = x[n0+4], c = x[n0+8], d = x[n0+12];
        float2 s0 = {a.x+c.x, a.y+c.y}, s1 = {a.x-c.x, a.y-c.y};
        float2 s2 = {b.x+d.x, b.y+d.y}, s3 = {b.x-d.x, b.y-d.y};
        t[n0*4+0] = {s0.x+s2.x, s0.y+s2.y};
        t[n0*4+2] = {s0.x-s2.x, s0.y-s2.y};
        if (DIR < 0) {
            t[n0*4+1] = {s1.x+s3.y, s1.y-s3.x};
            t[n0*4+3] = {s1.x-s3.y, s1.y+s3.x};
        } else {
            t[n0*4+1] = {s1.x-s3.y, s1.y+s3.x};
            t[n0*4+3] = {s1.x+s3.y, s1.y-s3.x};
        }
    }
    const float C1 = 0.92387953251128674f;
    const float S1_ = 0.38268343236508978f;
    const float R2 = 0.70710678118654752f;
    #define TW(idx, cc_, ss_) t[idx] = cmul(t[idx], (float2){cc_, DIR*(ss_)})
    TW(1*4+1, C1, S1_);   TW(1*4+2, R2, R2);    TW(1*4+3, S1_, C1);
    TW(2*4+1, R2, R2);    TW(2*4+2, 0.f, 1.f);  TW(2*4+3, -R2, R2);
    TW(3*4+1, S1_, C1);   TW(3*4+2, -R2, R2);   TW(3*4+3, -C1, -S1_);
    #undef TW
    #pragma unroll
    for (int k0 = 0; k0 < 4; ++k0) {
        float2 a = t[0+k0], b = t[4+k0], c = t[8+k0], d = t[12+k0];
        float2 s0 = {a.x+c.x, a.y+c.y}, s1 = {a.x-c.x, a.y-c.y};
        float2 s2 = {b.x+d.x, b.y+d.y}, s3 = {b.x-d.x, b.y-d.y};
        X[k0+0]  = {s0.x+s2.x, s0.y+s2.y};
        X[k0+8]  = {s0.x-s2.x, s0.y-s2.y};
        if (DIR < 0) {
            X[k0+4]  = {s1.x+s3.y, s1.y-s3.x};
            X[k0+12] = {s1.x-s3.y, s1.y+s3.x};
        } else {
            X[k0+4]  = {s1.x-s3.y, s1.y+s3.x};
            X[k0+12] = {s1.x+s3.y, s1.y-s3.x};
        }
    }
}

__device__ __forceinline__ void twiddle_apply(float2* y, float ang) {
    float s, c;
    __sincosf(ang, &s, &c);
    const float2 base = {c, s};
    float2 w = base;
    #pragma unroll
    for (int u = 1; u < 16; ++u) {
        y[u] = cmul(y[u], w);
        w = cmul(w, base);
    }
}

__global__ __launch_bounds__(768) void fft_attn_kernel3(
    const ushort* __restrict__ qt, const ushort* __restrict__ kt,
    const ushort* __restrict__ vt, ushort* __restrict__ ot16)
{
    __shared__ unsigned zA[2][FFT_N];   // Z1,Z2 spectra packed fp16 (32 KiB)
    __shared__ float2 bufB[FFT_N];      // V12 / H / inverse ws fp32 (32 KiB)

    const int tid = threadIdx.x;        // 0..767
    const int g   = tid >> 8;           // wave-uniform group 0,1,2
    const int lt  = tid & 255;          // local tid within group
    const int bid = blockIdx.x;         // [0, 2048)
    const int n   = bid >> 1;
    const int bp  = bid & 1;

    const size_t off0 = (size_t)n * M_TOTAL + (size_t)(2 * bp) * SEQ;
    const size_t off1 = off0 + SEQ;
    const _Float16* q0 = (const _Float16*)qt + off0;
    const _Float16* k0 = (const _Float16*)kt + off0;
    const _Float16* q1 = (const _Float16*)qt + off1;
    const _Float16* k1 = (const _Float16*)kt + off1;
    const _Float16* v0 = (const _Float16*)vt + off0;
    const _Float16* v1 = (const _Float16*)vt + off1;
    _Float16* o0 = (_Float16*)ot16 + off0;
    _Float16* o1 = (_Float16*)ot16 + off1;

    // ---- forward stage 1 (stride 256): group g loads+transforms buffer g
    {
        const float ang = -PI2 * (float)lt / 4096.f;
        float2 x[16], y[16];
        if (g == 0) {
            #pragma unroll
            for (int r = 0; r < 16; ++r)
                x[r] = { (float)q0[lt + 256*r], (float)k0[lt + 256*r] };
        } else if (g == 1) {
            #pragma unroll
            for (int r = 0; r < 16; ++r)
                x[r] = { (float)q1[lt + 256*r], (float)k1[lt + 256*r] };
        } else {
            #pragma unroll
            for (int r = 0; r < 16; ++r)
                x[r] = { (float)v0[lt + 256*r], (float)v1[lt + 256*r] };
        }
        dft16<-1>(x, y);
        twiddle_apply(y, ang);
        if (g < 2) {
            #pragma unroll
            for (int u = 0; u < 16; ++u) zA[g][phys(lt + 256*u)] = pk16(y[u]);
        } else {
            #pragma unroll
            for (int u = 0; u < 16; ++u) bufB[phys(lt + 256*u)] = y[u];
        }
    }
    __syncthreads();
    // ---- forward stage 2 (stride 16)
    {
        const int blk = lt >> 4, a = lt & 15;
        const int base = 256*blk + a;
        const float ang = -PI2 * (float)a / 256.f;
        float2 x[16], y[16];
        if (g < 2) {
            #pragma unroll
            for (int c = 0; c < 16; ++c) x[c] = upk16(zA[g][phys(base + 16*c)]);
        } else {
            #pragma unroll
            for (int c = 0; c < 16; ++c) x[c] = bufB[phys(base + 16*c)];
        }
        dft16<-1>(x, y);
        twiddle_apply(y, ang);
        if (g < 2) {
            #pragma unroll
            for (int c = 0; c < 16; ++c) zA[g][phys(base + 16*c)] = pk16(y[c]);
        } else {
            #pragma unroll
            for (int c = 0; c < 16; ++c) bufB[phys(base + 16*c)] = y[c];
        }
    }
    __syncthreads();
    // ---- forward stage 3 (contiguous 16)
    {
        const int base = 256*(lt >> 4) + 16*(lt & 15);
        float2 x[16], y[16];
        if (g < 2) {
            #pragma unroll
            for (int e = 0; e < 16; ++e) x[e] = upk16(zA[g][phys(base + e)]);
        } else {
            #pragma unroll
            for (int e = 0; e < 16; ++e) x[e] = bufB[phys(base + e)];
        }
        dft16<-1>(x, y);
        if (g < 2) {
            #pragma unroll
            for (int e = 0; e < 16; ++e) zA[g][phys(base + e)] = pk16(y[e]);
        } else {
            #pragma unroll
            for (int e = 0; e < 16; ++e) bufB[phys(base + e)] = y[e];
        }
    }
    __syncthreads();
    // ---- pointwise (r22-validated formula): slices s = g + 3*it over [0,16)
    float2 H[6];
    #pragma unroll
    for (int it = 0; it < 6; ++it) {
        const int s = g + 3 * it;
        if (s < 16) {
            const int p  = lt + s * 256;
            const int j  = ((p & 15) << 8) | (p & 0xF0) | (p >> 8);
            const int jn = (FFT_N - j) & (FFT_N - 1);
            const int pn = ((jn & 15) << 8) | (jn & 0xF0) | (jn >> 8);
            const float2 Vj = bufB[phys(p)];
            const float2 Vn = bufB[phys(pn)];
            const float2 V1 = { 0.5f*(Vj.x + Vn.x),  0.5f*(Vj.y - Vn.y) };
            const float2 V2 = { 0.5f*(Vj.y + Vn.y), -0.5f*(Vj.x - Vn.x) };
            float2 F1, F2;
            {
                const float2 Zj = upk16(zA[0][phys(p)]);
                const float2 Zn = upk16(zA[0][phys(pn)]);
                const float2 Q = { 0.5f*(Zj.x + Zn.x),  0.5f*(Zj.y - Zn.y) };
                const float2 K = { 0.5f*(Zj.y + Zn.y), -0.5f*(Zj.x - Zn.x) };
                const float2 G = { Q.x*K.x + Q.y*K.y, Q.y*K.x - Q.x*K.y };
                F1 = { G.x*V1.x - G.y*V1.y, G.x*V1.y + G.y*V1.x };
            }
            {
                const float2 Zj = upk16(zA[1][phys(p)]);
                const float2 Zn = upk16(zA[1][phys(pn)]);
                const float2 Q = { 0.5f*(Zj.x + Zn.x),  0.5f*(Zj.y - Zn.y) };
                const float2 K = { 0.5f*(Zj.y + Zn.y), -0.5f*(Zj.x - Zn.x) };
                const float2 G = { Q.x*K.x + Q.y*K.y, Q.y*K.x - Q.x*K.y };
                F2 = { G.x*V2.x - G.y*V2.y, G.x*V2.y + G.y*V2.x };
            }
            H[it] = { F1.x - F2.y, F1.y + F2.x };   // F1 + i*F2 (r22 fix)
        }
    }
    __syncthreads();          // all reads of bufB complete before overwrite
    #pragma unroll
    for (int it = 0; it < 6; ++it) {
        const int s = g + 3 * it;
        if (s < 16) bufB[phys(lt + s * 256)] = H[it];
    }
    __syncthreads();
    // ---- inverse stages (1 buffer, serial): group 0 only
    if (g == 0) {
        const int base = 256*(lt >> 4) + 16*(lt & 15);
        float2 x[16], y[16];
        #pragma unroll
        for (int d = 0; d < 16; ++d) x[d] = bufB[phys(base + d)];
        dft16<1>(x, y);
        #pragma unroll
        for (int p0 = 0; p0 < 16; ++p0) bufB[phys(base + p0)] = y[p0];
    }
    __syncthreads();
    if (g == 0) {
        const int blk = lt >> 4, p0 = lt & 15;
        const int base = 256*blk + p0;
        float2 x[16], y[16];
        #pragma unroll
        for (int c = 0; c < 16; ++c) x[c] = bufB[phys(base + 16*c)];
        twiddle_apply(x, PI2 * (float)p0 / 256.f);
        dft16<1>(x, y);
        #pragma unroll
        for (int p1 = 0; p1 < 16; ++p1) bufB[phys(base + 16*p1)] = y[p1];
    }
    __syncthreads();
    if (g == 0) {
        const int qq = lt;
        float2 x[16], y[16];
        #pragma unroll
        for (int t = 0; t < 16; ++t) x[t] = bufB[phys(qq + 256*t)];
        twiddle_apply(x, PI2 * (float)qq / 4096.f);
        dft16<1>(x, y);
        const float scale = 0.125f / 4096.f;   // 1/sqrt(64) * 1/N
        #pragma unroll
        for (int p2 = 0; p2 < 16; ++p2) {
            o0[qq + 256*p2] = (_Float16)(y[p2].x * scale);
            o1[qq + 256*p2] = (_Float16)(y[p2].y * scale);
        }
    }
}

// ---------------------------------------------------------------------------
// Transpose (fp16 in, fp16 out): ot16 [n][m] -> oth [m][k=n]  (r22-validated)
// ---------------------------------------------------------------------------
__global__ __launch_bounds__(256) void transpose_cvt_kernel(
    const ushort* __restrict__ ot, ushort* __restrict__ oth)
{
    __shared__ float tile[64][65];
    const int tid = threadIdx.x;
    const int m0  = blockIdx.x * 64;
    const int n0  = blockIdx.y * 64;
    const int r   = tid >> 4;
    const int c   = tid & 15;

    #pragma unroll
    for (int rr = 0; rr < 4; ++rr) {
        const int nl = r + rr * 16;
        ushort4 v = *(const ushort4*)(ot + (size_t)(n0 + nl) * M_TOTAL + m0 + c * 4);
        union { ushort u; _Float16 f; } cv;
        cv.u = v.x; tile[nl][c * 4 + 0] = (float)cv.f;
        cv.u = v.y; tile[nl][c * 4 + 1] = (float)cv.f;
        cv.u = v.z; tile[nl][c * 4 + 2] = (float)cv.f;
        cv.u = v.w; tile[nl][c * 4 + 3] = (float)cv.f;
    }
    __syncthreads();
    #pragma unroll
    for (int rr = 0; rr < 4; ++rr) {
        const int ml = r + rr * 16;
        ushort4 hh;
        union { _Float16 f; ushort u; } cv;
        cv.f = (_Float16)tile[c * 4 + 0][ml]; hh.x = cv.u;
        cv.f = (_Float16)tile[c * 4 + 1][ml]; hh.y = cv.u;
        cv.f = (_Float16)tile[c * 4 + 2][ml]; hh.z = cv.u;
        cv.f = (_Float16)tile[c * 4 + 3][ml]; hh.w = cv.u;
        *(ushort4*)(oth + (size_t)(m0 + ml) * HIDDEN + n0 + c * 4) = hh;
    }
}

// ---------------------------------------------------------------------------
// Output GEMM (r20/r22-VALIDATED, byte-identical)
// ---------------------------------------------------------------------------
__global__ __launch_bounds__(1024, 1) void gemm_out_mfma8(
    const ushort* __restrict__ oth, const ushort* __restrict__ woh,
    const float* __restrict__ bo, float* __restrict__ out)
{
    __shared__ ushort Ah[3][8192];
    __shared__ ushort Bh[3][8192];

    const int tid  = threadIdx.x;
    const int lane = tid & 63;
    const int wid  = tid >> 6;
    const int wr   = wid >> 2;
    const int wc   = wid & 3;
    const int m0   = blockIdx.x * 256;
    const int n0   = blockIdx.y * 256;

    const int row = tid >> 2;
    const int chS = (tid & 3) ^ ((row >> 1) & 3);

    const int fr = lane & 15;
    const int fc = lane >> 4;
    const int cc = (fc ^ ((fr >> 1) & 3)) * 8;

    f32x4 acc[4][4];
    #pragma unroll
    for (int rf = 0; rf < 4; ++rf)
        #pragma unroll
        for (int cf = 0; cf < 4; ++cf)
            acc[rf][cf] = (f32x4){0.f, 0.f, 0.f, 0.f};

#if HAVE_GLL
    #define OUT_STAGE(K0, SLOT) {                                                  \
        const size_t ga = (size_t)(m0 + row) * HIDDEN + (K0) + (size_t)chS * 8;    \
        const size_t gb = (size_t)(n0 + row) * HIDDEN + (K0) + (size_t)chS * 8;    \
        gload16(oth + ga, &Ah[SLOT][(size_t)tid * 8]);                             \
        gload16(woh + gb, &Bh[SLOT][(size_t)tid * 8]);                             \
    }
#else
    #define OUT_STAGE(K0, SLOT) {                                                  \
        const size_t ga = (size_t)(m0 + row) * HIDDEN + (K0) + (size_t)chS * 8;    \
        const size_t gb = (size_t)(n0 + row) * HIDDEN + (K0) + (size_t)chS * 8;    \
        *(f16x8*)&Ah[SLOT][(size_t)tid * 8] = *(const f16x8*)(oth + ga);           \
        *(f16x8*)&Bh[SLOT][(size_t)tid * 8] = *(const f16x8*)(woh + gb);           \
    }
#endif

    OUT_STAGE(0, 0);
    OUT_STAGE(32, 1);

    for (int ks = 0; ks < 32; ++ks) {
        const int slot = ks % 3;
#if HAVE_GLL
        if (ks == 31) { asm volatile("s_waitcnt vmcnt(0)" ::: "memory"); }
        else          { asm volatile("s_waitcnt vmcnt(2)" ::: "memory"); }
        __builtin_amdgcn_s_barrier();
        asm volatile("" ::: "memory");
#else
        __syncthreads();
#endif
        {
            const ushort* pAh = Ah[slot];
            const ushort* pBh = Bh[slot];
            f16x8 a_h[4], b_h[4];
            #pragma unroll
            for (int rf = 0; rf < 4; ++rf) {
                const int R = wr * 64 + rf * 16 + fr;
                a_h[rf] = *(const f16x8*)(pAh + R * 32 + cc);
            }
            #pragma unroll
            for (int cf = 0; cf < 4; ++cf) {
                const int R = wc * 64 + cf * 16 + fr;
                b_h[cf] = *(const f16x8*)(pBh + R * 32 + cc);
            }
            #pragma unroll
            for (int rf = 0; rf < 4; ++rf)
                #pragma unroll
                for (int cf = 0; cf < 4; ++cf)
                    acc[rf][cf] = __builtin_amdgcn_mfma_f32_16x16x32_f16(a_h[rf], b_h[cf], acc[rf][cf], 0, 0, 0);
        }
        if (ks + 2 < 32) { OUT_STAGE((ks + 2) * 32, (ks + 2) % 3); }
#if !HAVE_GLL
        __syncthreads();
#endif
    }
    #undef OUT_STAGE

    const int rq = lane >> 4;
    float bo_v[4];
    #pragma unroll
    for (int cf = 0; cf < 4; ++cf) bo_v[cf] = bo[n0 + wc * 64 + cf * 16 + fr];
    #pragma unroll
    for (int rf = 0; rf < 4; ++rf) {
        #pragma unroll
        for (int r = 0; r < 4; ++r) {
            const int ml = wr * 64 + rf * 16 + rq * 4 + r;
            float* dst = out + (size_t)(m0 + ml) * HIDDEN + n0 + wc * 64;
            #pragma unroll
            for (int cf = 0; cf < 4; ++cf)
                dst[cf * 16 + fr] = acc[rf][cf][r] + bo_v[cf];
        }
    }
}

// ---------------------------------------------------------------------------
// Buffers (ws = proven 201.3 MB; peak use 136.3 MB):
//   ws[0..100.66M):        qkvt fp16 [3][1024][16384]
//   ws[100.66..134.2M):    ot16 fp16 [1024][16384]
//   ws[134.2..136.3M):     woh fp16 [1024][1024]
//   After fft: oth (33.5 MB) aliases the dead qkvt region.
//   d_out stash: xh 33.55 + wh 6.29 = 39.8 MB < 67.1; dead before gemm_out.
// ---------------------------------------------------------------------------
extern "C" void kernel_launch(void* const* d_in, const int* in_sizes, int n_in,
                              void* d_out, int out_size, void* d_ws, size_t ws_size,
                              hipStream_t stream)
{
    const float* x  = (const float*)d_in[0];
    const float* Wq = (const float*)d_in[1];
    const float* bq = (const float*)d_in[2];
    const float* Wk = (const float*)d_in[3];
    const float* bk = (const float*)d_in[4];
    const float* Wv = (const float*)d_in[5];
    const float* bv = (const float*)d_in[6];
    const float* Wo = (const float*)d_in[7];
    const float* bo = (const float*)d_in[8];
    float* out = (float*)d_out;

    const size_t plane = (size_t)HIDDEN * M_TOTAL;   // 16.78M elements
    ushort* qkvt = (ushort*)d_ws;                    // fp16 [3][1024][16384]
    ushort* qt16 = qkvt;
    ushort* kt16 = qkvt + plane;
    ushort* vt16 = qkvt + 2 * plane;
    ushort* ot16 = qkvt + 3 * plane;                 // fp16 [1024][16384]
    ushort* woh  = ot16 + plane;                     // fp16 [1024][1024]

    // post-fft stash aliases dead qkvt region
    ushort* oth = qkvt;                              // [16384][1024] fp16

    // fp16 operand stash in d_out (dead before gemm_out writes d_out)
    ushort* xh  = (ushort*)d_out;                    // [16384][1024]
    ushort* wh  = xh + plane;                        // stacked [3072][1024]

    // pre-passes
    cvt16_kernel<<<(unsigned)(plane / 2048), 256, 0, stream>>>(x, xh);
    cvtW_kernel<<<dim3((unsigned)(WSZ / 2048), 4), 256, 0, stream>>>(
        Wq, Wk, Wv, Wo, wh, woh);

    // QKV projections
    gemm_qkv_mfma8<<<dim3(M_TOTAL / 256, 12), 1024, 0, stream>>>(
        xh, wh, bq, bk, bv, qkvt);

    // FFT attention: 2 sequences per block, 3 wave-groups, fp16 in/out
    fft_attn_kernel3<<<dim3(HIDDEN * BATCH / 2), 768, 0, stream>>>(
        qt16, kt16, vt16, ot16);

    // transpose ot16 -> oth [m][k]
    transpose_cvt_kernel<<<dim3(M_TOTAL / 64, HIDDEN / 64), 256, 0, stream>>>(
        ot16, oth);

    // output projection
    gemm_out_mfma8<<<dim3(M_TOTAL / 256, HIDDEN / 256), 1024, 0, stream>>>(
        oth, woh, bo, out);
}

// Round 24
// 244.029 us; speedup vs baseline: 1.0901x; 1.0901x over previous
//
#include <hip/hip_runtime.h>
#include <hip/hip_bf16.h>
#include <math.h>

#define HIDDEN   1024
#define HEADS    16
#define HEAD_DIM 64
#define BATCH    4
#define SEQ      4096
#define M_TOTAL  (BATCH * SEQ)          // 16384
#define FFT_N    4096
#define WSZ      ((size_t)HIDDEN * HIDDEN)
#define PI2      6.28318530717958647692f

typedef _Float16 f16x8 __attribute__((ext_vector_type(8)));   // 8 fp16 = 4 VGPR (MFMA A/B frag)
typedef float    f32x4 __attribute__((ext_vector_type(4)));   // MFMA C/D frag

#if defined(__has_builtin)
#if __has_builtin(__builtin_amdgcn_global_load_lds)
#define HAVE_GLL 1
#else
#define HAVE_GLL 0
#endif
#else
#define HAVE_GLL 0
#endif

#if HAVE_GLL
// async global->LDS, 16B/lane. dest = wave-uniform base + lane*16 (linear in slot).
__device__ __forceinline__ void gload16(const void* g, void* l) {
    __builtin_amdgcn_global_load_lds(
        (const __attribute__((address_space(1))) unsigned int*)g,
        (__attribute__((address_space(3))) unsigned int*)l,
        16, 0, 0);
}
#endif

__device__ __forceinline__ void cvt8_f16(float4 v0, float4 v1,
                                         ushort* __restrict__ d) {
    const float vv[8] = {v0.x, v0.y, v0.z, v0.w, v1.x, v1.y, v1.z, v1.w};
    f16x8 hv;
    #pragma unroll
    for (int e = 0; e < 8; ++e) hv[e] = (_Float16)vv[e];
    *(f16x8*)d = hv;
}

// ---------------------------------------------------------------------------
// Pre-pass kernels (r20/r22-validated)
// ---------------------------------------------------------------------------
__global__ __launch_bounds__(256) void cvt16_kernel(
    const float* __restrict__ src, ushort* __restrict__ h)
{
    const size_t i = ((size_t)blockIdx.x * 256 + threadIdx.x) * 8;
    float4 v0 = *(const float4*)(src + i);
    float4 v1 = *(const float4*)(src + i + 4);
    cvt8_f16(v0, v1, h + i);
}

__global__ __launch_bounds__(256) void cvtW_kernel(
    const float* __restrict__ Wq, const float* __restrict__ Wk,
    const float* __restrict__ Wv, const float* __restrict__ Wo,
    ushort* __restrict__ wh, ushort* __restrict__ woh)
{
    const int p = blockIdx.y;                 // 0=q 1=k 2=v 3=o
    const size_t i = ((size_t)blockIdx.x * 256 + threadIdx.x) * 8;
    const float* __restrict__ src = (p == 0) ? Wq : (p == 1 ? Wk : (p == 2 ? Wv : Wo));
    ushort* __restrict__ dst = (p < 3) ? (wh + (size_t)p * WSZ) : woh;
    float4 v0 = *(const float4*)(src + i);
    float4 v1 = *(const float4*)(src + i + 4);
    cvt8_f16(v0, v1, dst + i);
}

// ---------------------------------------------------------------------------
// QKV GEMM (r20/r22-VALIDATED, byte-identical)
// ---------------------------------------------------------------------------
__global__ __launch_bounds__(1024, 1) void gemm_qkv_mfma8(
    const ushort* __restrict__ xh, const ushort* __restrict__ wh,
    const float* __restrict__ bq, const float* __restrict__ bk,
    const float* __restrict__ bv,
    ushort* __restrict__ qkvt)
{
    __shared__ ushort Ah[3][8192];
    __shared__ ushort Bh[3][8192];

    const int tid  = threadIdx.x;
    const int lane = tid & 63;
    const int wid  = tid >> 6;
    const int wr   = wid >> 2;
    const int wc   = wid & 3;
    const int m0   = blockIdx.x * 256;
    const int ng0  = blockIdx.y * 256;
    const int p    = ng0 >> 10;
    const int n0p  = ng0 & 1023;

    const float* __restrict__ bias = (p == 0) ? bq : (p == 1 ? bk : bv);
    ushort* __restrict__ ct = qkvt + (size_t)p * HIDDEN * M_TOTAL;

    const int row = tid >> 2;
    const int chS = (tid & 3) ^ ((row >> 1) & 3);

    const int fr = lane & 15;
    const int fc = lane >> 4;
    const int cc = (fc ^ ((fr >> 1) & 3)) * 8;

    f32x4 acc[4][4];
    #pragma unroll
    for (int rf = 0; rf < 4; ++rf)
        #pragma unroll
        for (int cf = 0; cf < 4; ++cf)
            acc[rf][cf] = (f32x4){0.f, 0.f, 0.f, 0.f};

#if HAVE_GLL
    #define QKV_STAGE(K0, SLOT) {                                                  \
        const size_t gw = (size_t)(ng0 + row) * HIDDEN + (K0) + (size_t)chS * 8;   \
        const size_t gx = (size_t)(m0 + row) * HIDDEN + (K0) + (size_t)chS * 8;    \
        gload16(wh + gw, &Ah[SLOT][(size_t)tid * 8]);                              \
        gload16(xh + gx, &Bh[SLOT][(size_t)tid * 8]);                              \
    }
#else
    #define QKV_STAGE(K0, SLOT) {                                                  \
        const size_t gw = (size_t)(ng0 + row) * HIDDEN + (K0) + (size_t)chS * 8;   \
        const size_t gx = (size_t)(m0 + row) * HIDDEN + (K0) + (size_t)chS * 8;    \
        *(f16x8*)&Ah[SLOT][(size_t)tid * 8] = *(const f16x8*)(wh + gw);            \
        *(f16x8*)&Bh[SLOT][(size_t)tid * 8] = *(const f16x8*)(xh + gx);            \
    }
#endif

    QKV_STAGE(0, 0);
    QKV_STAGE(32, 1);

    for (int ks = 0; ks < 32; ++ks) {
        const int slot = ks % 3;
#if HAVE_GLL
        if (ks == 31) { asm volatile("s_waitcnt vmcnt(0)" ::: "memory"); }
        else          { asm volatile("s_waitcnt vmcnt(2)" ::: "memory"); }
        __builtin_amdgcn_s_barrier();
        asm volatile("" ::: "memory");
#else
        __syncthreads();
#endif
        {
            const ushort* pAh = Ah[slot];
            const ushort* pBh = Bh[slot];
            f16x8 a_h[4], b_h[4];
            #pragma unroll
            for (int rf = 0; rf < 4; ++rf) {
                const int R = wr * 64 + rf * 16 + fr;
                a_h[rf] = *(const f16x8*)(pAh + R * 32 + cc);
            }
            #pragma unroll
            for (int cf = 0; cf < 4; ++cf) {
                const int R = wc * 64 + cf * 16 + fr;
                b_h[cf] = *(const f16x8*)(pBh + R * 32 + cc);
            }
            #pragma unroll
            for (int rf = 0; rf < 4; ++rf)
                #pragma unroll
                for (int cf = 0; cf < 4; ++cf)
                    acc[rf][cf] = __builtin_amdgcn_mfma_f32_16x16x32_f16(a_h[rf], b_h[cf], acc[rf][cf], 0, 0, 0);
        }
        if (ks + 2 < 32) { QKV_STAGE((ks + 2) * 32, (ks + 2) % 3); }
#if !HAVE_GLL
        __syncthreads();
#endif
    }
    #undef QKV_STAGE

    const int rq = lane >> 4;
    #pragma unroll
    for (int rf = 0; rf < 4; ++rf) {
        #pragma unroll
        for (int r = 0; r < 4; ++r) {
            const int nl = wr * 64 + rf * 16 + rq * 4 + r;
            const float bv = bias[n0p + nl];
            ushort* dst = ct + (size_t)(n0p + nl) * M_TOTAL + m0 + wc * 64;
            #pragma unroll
            for (int cf = 0; cf < 4; ++cf) {
                union { _Float16 f; ushort u; } cvt;
                cvt.f = (_Float16)(acc[rf][cf][r] + bv);
                dst[cf * 16 + fr] = cvt.u;
            }
        }
    }
}

// ---------------------------------------------------------------------------
// Radix-16 FFT, paired sequences (r22-VALIDATED math/structure, 256 thr).
// THIS ROUND: all 3 LDS buffers packed fp16 (48 KiB -> 3 blocks/CU, was 2)
// + 4-byte-word swizzle phys32 (r22's phys was float2-tuned; conflicts 3.1M).
// Overflow: pointwise stores H' = H/4096 (ifft 1/N folded in, exact by
// linearity; |H'|~O(100)); final scale = 1/8. Inverse intermediates < 65504.
// ---------------------------------------------------------------------------
__device__ __forceinline__ float2 cmul(float2 a, float2 b) {
    return {a.x*b.x - a.y*b.y, a.x*b.y + a.y*b.x};
}

// 4-byte-word LDS swizzle: involution, conflict-free (2 lanes/bank) for all
// three stage patterns (stride-256, stride-16, contig-16).
__device__ __forceinline__ int phys32(int p) {
    return p ^ ((p >> 4) & 15) ^ (((p >> 8) & 1) << 4);
}

__device__ __forceinline__ unsigned pk16(float2 v) {
    union { _Float16 f[2]; unsigned u; } c;
    c.f[0] = (_Float16)v.x; c.f[1] = (_Float16)v.y;
    return c.u;
}
__device__ __forceinline__ float2 upk16(unsigned u) {
    union { unsigned uu; _Float16 f[2]; } c; c.uu = u;
    return (float2){(float)c.f[0], (float)c.f[1]};
}

template<int DIR>
__device__ __forceinline__ void dft16(const float2* x, float2* X) {
    float2 t[16];
    #pragma unroll
    for (int n0 = 0; n0 < 4; ++n0) {
        float2 a = x[n0], b = x[n0+4], c = x[n0+8], d = x[n0+12];
        float2 s0 = {a.x+c.x, a.y+c.y}, s1 = {a.x-c.x, a.y-c.y};
        float2 s2 = {b.x+d.x, b.y+d.y}, s3 = {b.x-d.x, b.y-d.y};
        t[n0*4+0] = {s0.x+s2.x, s0.y+s2.y};
        t[n0*4+2] = {s0.x-s2.x, s0.y-s2.y};
        if (DIR < 0) {
            t[n0*4+1] = {s1.x+s3.y, s1.y-s3.x};
            t[n0*4+3] = {s1.x-s3.y, s1.y+s3.x};
        } else {
            t[n0*4+1] = {s1.x-s3.y, s1.y+s3.x};
            t[n0*4+3] = {s1.x+s3.y, s1.y-s3.x};
        }
    }
    const float C1 = 0.92387953251128674f;
    const float S1_ = 0.38268343236508978f;
    const float R2 = 0.70710678118654752f;
    #define TW(idx, cc_, ss_) t[idx] = cmul(t[idx], (float2){cc_, DIR*(ss_)})
    TW(1*4+1, C1, S1_);   TW(1*4+2, R2, R2);    TW(1*4+3, S1_, C1);
    TW(2*4+1, R2, R2);    TW(2*4+2, 0.f, 1.f);  TW(2*4+3, -R2, R2);
    TW(3*4+1, S1_, C1);   TW(3*4+2, -R2, R2);   TW(3*4+3, -C1, -S1_);
    #undef TW
    #pragma unroll
    for (int k0 = 0; k0 < 4; ++k0) {
        float2 a = t[0+k0], b = t[4+k0], c = t[8+k0], d = t[12+k0];
        float2 s0 = {a.x+c.x, a.y+c.y}, s1 = {a.x-c.x, a.y-c.y};
        float2 s2 = {b.x+d.x, b.y+d.y}, s3 = {b.x-d.x, b.y-d.y};
        X[k0+0]  = {s0.x+s2.x, s0.y+s2.y};
        X[k0+8]  = {s0.x-s2.x, s0.y-s2.y};
        if (DIR < 0) {
            X[k0+4]  = {s1.x+s3.y, s1.y-s3.x};
            X[k0+12] = {s1.x-s3.y, s1.y+s3.x};
        } else {
            X[k0+4]  = {s1.x-s3.y, s1.y+s3.x};
            X[k0+12] = {s1.x+s3.y, s1.y-s3.x};
        }
    }
}

__device__ __forceinline__ void twiddle_apply(float2* y, float ang) {
    float s, c;
    __sincosf(ang, &s, &c);
    const float2 base = {c, s};
    float2 w = base;
    #pragma unroll
    for (int u = 1; u < 16; ++u) {
        y[u] = cmul(y[u], w);
        w = cmul(w, base);
    }
}

__global__ __launch_bounds__(256) void fft_attn_kernel4(
    const ushort* __restrict__ qt, const ushort* __restrict__ kt,
    const ushort* __restrict__ vt, ushort* __restrict__ ot16)
{
    __shared__ unsigned zA[3][FFT_N];   // Z1, Z2, V12/H' packed fp16 (48 KiB)

    const int tid = threadIdx.x;
    const int bid = blockIdx.x;          // [0, 2048)
    const int n   = bid >> 1;
    const int bp  = bid & 1;

    const size_t off0 = (size_t)n * M_TOTAL + (size_t)(2 * bp) * SEQ;
    const size_t off1 = off0 + SEQ;
    const _Float16* q0 = (const _Float16*)qt + off0;
    const _Float16* k0 = (const _Float16*)kt + off0;
    const _Float16* q1 = (const _Float16*)qt + off1;
    const _Float16* k1 = (const _Float16*)kt + off1;
    const _Float16* v0 = (const _Float16*)vt + off0;
    const _Float16* v1 = (const _Float16*)vt + off1;
    _Float16* o0 = (_Float16*)ot16 + off0;
    _Float16* o1 = (_Float16*)ot16 + off1;

    // ---- forward stage 1 (stride 256) from global, all 3 buffers
    {
        const float ang = -PI2 * (float)tid / 4096.f;
        {   // Z1 = q0 + i k0
            float2 x[16], y[16];
            #pragma unroll
            for (int r = 0; r < 16; ++r)
                x[r] = { (float)q0[tid + 256*r], (float)k0[tid + 256*r] };
            dft16<-1>(x, y);
            twiddle_apply(y, ang);
            #pragma unroll
            for (int u = 0; u < 16; ++u) zA[0][phys32(tid + 256*u)] = pk16(y[u]);
        }
        {   // Z2 = q1 + i k1
            float2 x[16], y[16];
            #pragma unroll
            for (int r = 0; r < 16; ++r)
                x[r] = { (float)q1[tid + 256*r], (float)k1[tid + 256*r] };
            dft16<-1>(x, y);
            twiddle_apply(y, ang);
            #pragma unroll
            for (int u = 0; u < 16; ++u) zA[1][phys32(tid + 256*u)] = pk16(y[u]);
        }
        {   // V12 = v0 + i v1
            float2 x[16], y[16];
            #pragma unroll
            for (int r = 0; r < 16; ++r)
                x[r] = { (float)v0[tid + 256*r], (float)v1[tid + 256*r] };
            dft16<-1>(x, y);
            twiddle_apply(y, ang);
            #pragma unroll
            for (int u = 0; u < 16; ++u) zA[2][phys32(tid + 256*u)] = pk16(y[u]);
        }
    }
    __syncthreads();
    // ---- forward stage 2 (stride 16)
    {
        const int blk = tid >> 4, a = tid & 15;
        const int base = 256*blk + a;
        const float ang = -PI2 * (float)a / 256.f;
        #pragma unroll
        for (int d = 0; d < 3; ++d) {
            float2 x[16], y[16];
            #pragma unroll
            for (int c = 0; c < 16; ++c) x[c] = upk16(zA[d][phys32(base + 16*c)]);
            dft16<-1>(x, y);
            twiddle_apply(y, ang);
            #pragma unroll
            for (int c = 0; c < 16; ++c) zA[d][phys32(base + 16*c)] = pk16(y[c]);
        }
    }
    __syncthreads();
    // ---- forward stage 3 (contiguous 16)
    {
        const int base = 256*(tid >> 4) + 16*(tid & 15);
        #pragma unroll
        for (int d = 0; d < 3; ++d) {
            float2 x[16], y[16];
            #pragma unroll
            for (int e = 0; e < 16; ++e) x[e] = upk16(zA[d][phys32(base + e)]);
            dft16<-1>(x, y);
            #pragma unroll
            for (int e = 0; e < 16; ++e) zA[d][phys32(base + e)] = pk16(y[e]);
        }
    }
    __syncthreads();
    // ---- pointwise (r22-validated formula): H' = (F1 + i*F2)/4096
    float2 H[16];
    #pragma unroll
    for (int it = 0; it < 16; ++it) {
        const int p  = tid + it * 256;
        const int j  = ((p & 15) << 8) | (p & 0xF0) | (p >> 8);
        const int jn = (FFT_N - j) & (FFT_N - 1);
        const int pn = ((jn & 15) << 8) | (jn & 0xF0) | (jn >> 8);
        const float2 Vj = upk16(zA[2][phys32(p)]);
        const float2 Vn = upk16(zA[2][phys32(pn)]);
        const float2 V1 = { 0.5f*(Vj.x + Vn.x),  0.5f*(Vj.y - Vn.y) };
        const float2 V2 = { 0.5f*(Vj.y + Vn.y), -0.5f*(Vj.x - Vn.x) };
        float2 F1, F2;
        {
            const float2 Zj = upk16(zA[0][phys32(p)]);
            const float2 Zn = upk16(zA[0][phys32(pn)]);
            const float2 Q = { 0.5f*(Zj.x + Zn.x),  0.5f*(Zj.y - Zn.y) };
            const float2 K = { 0.5f*(Zj.y + Zn.y), -0.5f*(Zj.x - Zn.x) };
            const float2 G = { Q.x*K.x + Q.y*K.y, Q.y*K.x - Q.x*K.y };
            F1 = { G.x*V1.x - G.y*V1.y, G.x*V1.y + G.y*V1.x };
        }
        {
            const float2 Zj = upk16(zA[1][phys32(p)]);
            const float2 Zn = upk16(zA[1][phys32(pn)]);
            const float2 Q = { 0.5f*(Zj.x + Zn.x),  0.5f*(Zj.y - Zn.y) };
            const float2 K = { 0.5f*(Zj.y + Zn.y), -0.5f*(Zj.x - Zn.x) };
            const float2 G = { Q.x*K.x + Q.y*K.y, Q.y*K.x - Q.x*K.y };
            F2 = { G.x*V2.x - G.y*V2.y, G.x*V2.y + G.y*V2.x };
        }
        const float inv_n = 1.0f / 4096.f;
        H[it] = { (F1.x - F2.y) * inv_n, (F1.y + F2.x) * inv_n };   // (F1 + i*F2)/N
    }
    __syncthreads();          // all reads of zA[2] complete before overwrite
    #pragma unroll
    for (int it = 0; it < 16; ++it)
        zA[2][phys32(tid + it * 256)] = pk16(H[it]);
    __syncthreads();
    // ---- inverse stage A (contiguous 16), buffer zA[2]
    {
        const int base = 256*(tid >> 4) + 16*(tid & 15);
        float2 x[16], y[16];
        #pragma unroll
        for (int d = 0; d < 16; ++d) x[d] = upk16(zA[2][phys32(base + d)]);
        dft16<1>(x, y);
        #pragma unroll
        for (int p0 = 0; p0 < 16; ++p0) zA[2][phys32(base + p0)] = pk16(y[p0]);
    }
    __syncthreads();
    // ---- inverse stage B (stride 16), input twiddle
    {
        const int blk = tid >> 4, p0 = tid & 15;
        const int base = 256*blk + p0;
        float2 x[16], y[16];
        #pragma unroll
        for (int c = 0; c < 16; ++c) x[c] = upk16(zA[2][phys32(base + 16*c)]);
        twiddle_apply(x, PI2 * (float)p0 / 256.f);
        dft16<1>(x, y);
        #pragma unroll
        for (int p1 = 0; p1 < 16; ++p1) zA[2][phys32(base + 16*p1)] = pk16(y[p1]);
    }
    __syncthreads();
    // ---- inverse stage C (stride 256), twiddle, fp16 dual store (scale 1/8)
    {
        const int qq = tid;
        float2 x[16], y[16];
        #pragma unroll
        for (int t = 0; t < 16; ++t) x[t] = upk16(zA[2][phys32(qq + 256*t)]);
        twiddle_apply(x, PI2 * (float)qq / 4096.f);
        dft16<1>(x, y);
        const float scale = 0.125f;   // 1/sqrt(64); 1/N already folded into H'
        #pragma unroll
        for (int p2 = 0; p2 < 16; ++p2) {
            o0[qq + 256*p2] = (_Float16)(y[p2].x * scale);
            o1[qq + 256*p2] = (_Float16)(y[p2].y * scale);
        }
    }
}

// ---------------------------------------------------------------------------
// Transpose (fp16 in, fp16 out): ot16 [n][m] -> oth [m][k=n]  (r22-validated)
// ---------------------------------------------------------------------------
__global__ __launch_bounds__(256) void transpose_cvt_kernel(
    const ushort* __restrict__ ot, ushort* __restrict__ oth)
{
    __shared__ float tile[64][65];
    const int tid = threadIdx.x;
    const int m0  = blockIdx.x * 64;
    const int n0  = blockIdx.y * 64;
    const int r   = tid >> 4;
    const int c   = tid & 15;

    #pragma unroll
    for (int rr = 0; rr < 4; ++rr) {
        const int nl = r + rr * 16;
        ushort4 v = *(const ushort4*)(ot + (size_t)(n0 + nl) * M_TOTAL + m0 + c * 4);
        union { ushort u; _Float16 f; } cv;
        cv.u = v.x; tile[nl][c * 4 + 0] = (float)cv.f;
        cv.u = v.y; tile[nl][c * 4 + 1] = (float)cv.f;
        cv.u = v.z; tile[nl][c * 4 + 2] = (float)cv.f;
        cv.u = v.w; tile[nl][c * 4 + 3] = (float)cv.f;
    }
    __syncthreads();
    #pragma unroll
    for (int rr = 0; rr < 4; ++rr) {
        const int ml = r + rr * 16;
        ushort4 hh;
        union { _Float16 f; ushort u; } cv;
        cv.f = (_Float16)tile[c * 4 + 0][ml]; hh.x = cv.u;
        cv.f = (_Float16)tile[c * 4 + 1][ml]; hh.y = cv.u;
        cv.f = (_Float16)tile[c * 4 + 2][ml]; hh.z = cv.u;
        cv.f = (_Float16)tile[c * 4 + 3][ml]; hh.w = cv.u;
        *(ushort4*)(oth + (size_t)(m0 + ml) * HIDDEN + n0 + c * 4) = hh;
    }
}

// ---------------------------------------------------------------------------
// Output GEMM (r20/r22-VALIDATED, byte-identical)
// ---------------------------------------------------------------------------
__global__ __launch_bounds__(1024, 1) void gemm_out_mfma8(
    const ushort* __restrict__ oth, const ushort* __restrict__ woh,
    const float* __restrict__ bo, float* __restrict__ out)
{
    __shared__ ushort Ah[3][8192];
    __shared__ ushort Bh[3][8192];

    const int tid  = threadIdx.x;
    const int lane = tid & 63;
    const int wid  = tid >> 6;
    const int wr   = wid >> 2;
    const int wc   = wid & 3;
    const int m0   = blockIdx.x * 256;
    const int n0   = blockIdx.y * 256;

    const int row = tid >> 2;
    const int chS = (tid & 3) ^ ((row >> 1) & 3);

    const int fr = lane & 15;
    const int fc = lane >> 4;
    const int cc = (fc ^ ((fr >> 1) & 3)) * 8;

    f32x4 acc[4][4];
    #pragma unroll
    for (int rf = 0; rf < 4; ++rf)
        #pragma unroll
        for (int cf = 0; cf < 4; ++cf)
            acc[rf][cf] = (f32x4){0.f, 0.f, 0.f, 0.f};

#if HAVE_GLL
    #define OUT_STAGE(K0, SLOT) {                                                  \
        const size_t ga = (size_t)(m0 + row) * HIDDEN + (K0) + (size_t)chS * 8;    \
        const size_t gb = (size_t)(n0 + row) * HIDDEN + (K0) + (size_t)chS * 8;    \
        gload16(oth + ga, &Ah[SLOT][(size_t)tid * 8]);                             \
        gload16(woh + gb, &Bh[SLOT][(size_t)tid * 8]);                             \
    }
#else
    #define OUT_STAGE(K0, SLOT) {                                                  \
        const size_t ga = (size_t)(m0 + row) * HIDDEN + (K0) + (size_t)chS * 8;    \
        const size_t gb = (size_t)(n0 + row) * HIDDEN + (K0) + (size_t)chS * 8;    \
        *(f16x8*)&Ah[SLOT][(size_t)tid * 8] = *(const f16x8*)(oth + ga);           \
        *(f16x8*)&Bh[SLOT][(size_t)tid * 8] = *(const f16x8*)(woh + gb);           \
    }
#endif

    OUT_STAGE(0, 0);
    OUT_STAGE(32, 1);

    for (int ks = 0; ks < 32; ++ks) {
        const int slot = ks % 3;
#if HAVE_GLL
        if (ks == 31) { asm volatile("s_waitcnt vmcnt(0)" ::: "memory"); }
        else          { asm volatile("s_waitcnt vmcnt(2)" ::: "memory"); }
        __builtin_amdgcn_s_barrier();
        asm volatile("" ::: "memory");
#else
        __syncthreads();
#endif
        {
            const ushort* pAh = Ah[slot];
            const ushort* pBh = Bh[slot];
            f16x8 a_h[4], b_h[4];
            #pragma unroll
            for (int rf = 0; rf < 4; ++rf) {
                const int R = wr * 64 + rf * 16 + fr;
                a_h[rf] = *(const f16x8*)(pAh + R * 32 + cc);
            }
            #pragma unroll
            for (int cf = 0; cf < 4; ++cf) {
                const int R = wc * 64 + cf * 16 + fr;
                b_h[cf] = *(const f16x8*)(pBh + R * 32 + cc);
            }
            #pragma unroll
            for (int rf = 0; rf < 4; ++rf)
                #pragma unroll
                for (int cf = 0; cf < 4; ++cf)
                    acc[rf][cf] = __builtin_amdgcn_mfma_f32_16x16x32_f16(a_h[rf], b_h[cf], acc[rf][cf], 0, 0, 0);
        }
        if (ks + 2 < 32) { OUT_STAGE((ks + 2) * 32, (ks + 2) % 3); }
#if !HAVE_GLL
        __syncthreads();
#endif
    }
    #undef OUT_STAGE

    const int rq = lane >> 4;
    float bo_v[4];
    #pragma unroll
    for (int cf = 0; cf < 4; ++cf) bo_v[cf] = bo[n0 + wc * 64 + cf * 16 + fr];
    #pragma unroll
    for (int rf = 0; rf < 4; ++rf) {
        #pragma unroll
        for (int r = 0; r < 4; ++r) {
            const int ml = wr * 64 + rf * 16 + rq * 4 + r;
            float* dst = out + (size_t)(m0 + ml) * HIDDEN + n0 + wc * 64;
            #pragma unroll
            for (int cf = 0; cf < 4; ++cf)
                dst[cf * 16 + fr] = acc[rf][cf][r] + bo_v[cf];
        }
    }
}

// ---------------------------------------------------------------------------
// Buffers (ws = proven 201.3 MB; peak use 136.3 MB):
//   ws[0..100.66M):        qkvt fp16 [3][1024][16384]
//   ws[100.66..134.2M):    ot16 fp16 [1024][16384]
//   ws[134.2..136.3M):     woh fp16 [1024][1024]
//   After fft: oth (33.5 MB) aliases the dead qkvt region.
//   d_out stash: xh 33.55 + wh 6.29 = 39.8 MB < 67.1; dead before gemm_out.
// ---------------------------------------------------------------------------
extern "C" void kernel_launch(void* const* d_in, const int* in_sizes, int n_in,
                              void* d_out, int out_size, void* d_ws, size_t ws_size,
                              hipStream_t stream)
{
    const float* x  = (const float*)d_in[0];
    const float* Wq = (const float*)d_in[1];
    const float* bq = (const float*)d_in[2];
    const float* Wk = (const float*)d_in[3];
    const float* bk = (const float*)d_in[4];
    const float* Wv = (const float*)d_in[5];
    const float* bv = (const float*)d_in[6];
    const float* Wo = (const float*)d_in[7];
    const float* bo = (const float*)d_in[8];
    float* out = (float*)d_out;

    const size_t plane = (size_t)HIDDEN * M_TOTAL;   // 16.78M elements
    ushort* qkvt = (ushort*)d_ws;                    // fp16 [3][1024][16384]
    ushort* qt16 = qkvt;
    ushort* kt16 = qkvt + plane;
    ushort* vt16 = qkvt + 2 * plane;
    ushort* ot16 = qkvt + 3 * plane;                 // fp16 [1024][16384]
    ushort* woh  = ot16 + plane;                     // fp16 [1024][1024]

    // post-fft stash aliases dead qkvt region
    ushort* oth = qkvt;                              // [16384][1024] fp16

    // fp16 operand stash in d_out (dead before gemm_out writes d_out)
    ushort* xh  = (ushort*)d_out;                    // [16384][1024]
    ushort* wh  = xh + plane;                        // stacked [3072][1024]

    // pre-passes
    cvt16_kernel<<<(unsigned)(plane / 2048), 256, 0, stream>>>(x, xh);
    cvtW_kernel<<<dim3((unsigned)(WSZ / 2048), 4), 256, 0, stream>>>(
        Wq, Wk, Wv, Wo, wh, woh);

    // QKV projections
    gemm_qkv_mfma8<<<dim3(M_TOTAL / 256, 12), 1024, 0, stream>>>(
        xh, wh, bq, bk, bv, qkvt);

    // FFT attention: 2 sequences per block, 48 KiB LDS (3 blk/CU), fp16 in/out
    fft_attn_kernel4<<<dim3(HIDDEN * BATCH / 2), 256, 0, stream>>>(
        qt16, kt16, vt16, ot16);

    // transpose ot16 -> oth [m][k]
    transpose_cvt_kernel<<<dim3(M_TOTAL / 64, HIDDEN / 64), 256, 0, stream>>>(
        ot16, oth);

    // output projection
    gemm_out_mfma8<<<dim3(M_TOTAL / 256, HIDDEN / 256), 1024, 0, stream>>>(
        oth, woh, bo, out);
}

// Round 25
// 242.560 us; speedup vs baseline: 1.0967x; 1.0061x over previous
//
#include <hip/hip_runtime.h>
#include <hip/hip_bf16.h>
#include <math.h>

#define HIDDEN   1024
#define HEADS    16
#define HEAD_DIM 64
#define BATCH    4
#define SEQ      4096
#define M_TOTAL  (BATCH * SEQ)          // 16384
#define FFT_N    4096
#define WSZ      ((size_t)HIDDEN * HIDDEN)
#define PI2      6.28318530717958647692f

typedef _Float16 f16x8 __attribute__((ext_vector_type(8)));   // 8 fp16 = 4 VGPR (MFMA A/B frag)
typedef float    f32x4 __attribute__((ext_vector_type(4)));   // MFMA C/D frag

#if defined(__has_builtin)
#if __has_builtin(__builtin_amdgcn_global_load_lds)
#define HAVE_GLL 1
#else
#define HAVE_GLL 0
#endif
#else
#define HAVE_GLL 0
#endif

#if HAVE_GLL
// async global->LDS, 16B/lane. dest = wave-uniform base + lane*16 (linear in slot).
__device__ __forceinline__ void gload16(const void* g, void* l) {
    __builtin_amdgcn_global_load_lds(
        (const __attribute__((address_space(1))) unsigned int*)g,
        (__attribute__((address_space(3))) unsigned int*)l,
        16, 0, 0);
}
#endif

__device__ __forceinline__ void cvt8_f16(float4 v0, float4 v1,
                                         ushort* __restrict__ d) {
    const float vv[8] = {v0.x, v0.y, v0.z, v0.w, v1.x, v1.y, v1.z, v1.w};
    f16x8 hv;
    #pragma unroll
    for (int e = 0; e < 8; ++e) hv[e] = (_Float16)vv[e];
    *(f16x8*)d = hv;
}

// ---------------------------------------------------------------------------
// Pre-pass kernels (r20/r22-validated)
// ---------------------------------------------------------------------------
__global__ __launch_bounds__(256) void cvt16_kernel(
    const float* __restrict__ src, ushort* __restrict__ h)
{
    const size_t i = ((size_t)blockIdx.x * 256 + threadIdx.x) * 8;
    float4 v0 = *(const float4*)(src + i);
    float4 v1 = *(const float4*)(src + i + 4);
    cvt8_f16(v0, v1, h + i);
}

__global__ __launch_bounds__(256) void cvtW_kernel(
    const float* __restrict__ Wq, const float* __restrict__ Wk,
    const float* __restrict__ Wv, const float* __restrict__ Wo,
    ushort* __restrict__ wh, ushort* __restrict__ woh)
{
    const int p = blockIdx.y;                 // 0=q 1=k 2=v 3=o
    const size_t i = ((size_t)blockIdx.x * 256 + threadIdx.x) * 8;
    const float* __restrict__ src = (p == 0) ? Wq : (p == 1 ? Wk : (p == 2 ? Wv : Wo));
    ushort* __restrict__ dst = (p < 3) ? (wh + (size_t)p * WSZ) : woh;
    float4 v0 = *(const float4*)(src + i);
    float4 v1 = *(const float4*)(src + i + 4);
    cvt8_f16(v0, v1, dst + i);
}

// ---------------------------------------------------------------------------
// QKV GEMM (r20/r22/r24-VALIDATED, byte-identical)
// ---------------------------------------------------------------------------
__global__ __launch_bounds__(1024, 1) void gemm_qkv_mfma8(
    const ushort* __restrict__ xh, const ushort* __restrict__ wh,
    const float* __restrict__ bq, const float* __restrict__ bk,
    const float* __restrict__ bv,
    ushort* __restrict__ qkvt)
{
    __shared__ ushort Ah[3][8192];
    __shared__ ushort Bh[3][8192];

    const int tid  = threadIdx.x;
    const int lane = tid & 63;
    const int wid  = tid >> 6;
    const int wr   = wid >> 2;
    const int wc   = wid & 3;
    const int m0   = blockIdx.x * 256;
    const int ng0  = blockIdx.y * 256;
    const int p    = ng0 >> 10;
    const int n0p  = ng0 & 1023;

    const float* __restrict__ bias = (p == 0) ? bq : (p == 1 ? bk : bv);
    ushort* __restrict__ ct = qkvt + (size_t)p * HIDDEN * M_TOTAL;

    const int row = tid >> 2;
    const int chS = (tid & 3) ^ ((row >> 1) & 3);

    const int fr = lane & 15;
    const int fc = lane >> 4;
    const int cc = (fc ^ ((fr >> 1) & 3)) * 8;

    f32x4 acc[4][4];
    #pragma unroll
    for (int rf = 0; rf < 4; ++rf)
        #pragma unroll
        for (int cf = 0; cf < 4; ++cf)
            acc[rf][cf] = (f32x4){0.f, 0.f, 0.f, 0.f};

#if HAVE_GLL
    #define QKV_STAGE(K0, SLOT) {                                                  \
        const size_t gw = (size_t)(ng0 + row) * HIDDEN + (K0) + (size_t)chS * 8;   \
        const size_t gx = (size_t)(m0 + row) * HIDDEN + (K0) + (size_t)chS * 8;    \
        gload16(wh + gw, &Ah[SLOT][(size_t)tid * 8]);                              \
        gload16(xh + gx, &Bh[SLOT][(size_t)tid * 8]);                              \
    }
#else
    #define QKV_STAGE(K0, SLOT) {                                                  \
        const size_t gw = (size_t)(ng0 + row) * HIDDEN + (K0) + (size_t)chS * 8;   \
        const size_t gx = (size_t)(m0 + row) * HIDDEN + (K0) + (size_t)chS * 8;    \
        *(f16x8*)&Ah[SLOT][(size_t)tid * 8] = *(const f16x8*)(wh + gw);            \
        *(f16x8*)&Bh[SLOT][(size_t)tid * 8] = *(const f16x8*)(xh + gx);            \
    }
#endif

    QKV_STAGE(0, 0);
    QKV_STAGE(32, 1);

    for (int ks = 0; ks < 32; ++ks) {
        const int slot = ks % 3;
#if HAVE_GLL
        if (ks == 31) { asm volatile("s_waitcnt vmcnt(0)" ::: "memory"); }
        else          { asm volatile("s_waitcnt vmcnt(2)" ::: "memory"); }
        __builtin_amdgcn_s_barrier();
        asm volatile("" ::: "memory");
#else
        __syncthreads();
#endif
        {
            const ushort* pAh = Ah[slot];
            const ushort* pBh = Bh[slot];
            f16x8 a_h[4], b_h[4];
            #pragma unroll
            for (int rf = 0; rf < 4; ++rf) {
                const int R = wr * 64 + rf * 16 + fr;
                a_h[rf] = *(const f16x8*)(pAh + R * 32 + cc);
            }
            #pragma unroll
            for (int cf = 0; cf < 4; ++cf) {
                const int R = wc * 64 + cf * 16 + fr;
                b_h[cf] = *(const f16x8*)(pBh + R * 32 + cc);
            }
            #pragma unroll
            for (int rf = 0; rf < 4; ++rf)
                #pragma unroll
                for (int cf = 0; cf < 4; ++cf)
                    acc[rf][cf] = __builtin_amdgcn_mfma_f32_16x16x32_f16(a_h[rf], b_h[cf], acc[rf][cf], 0, 0, 0);
        }
        if (ks + 2 < 32) { QKV_STAGE((ks + 2) * 32, (ks + 2) % 3); }
#if !HAVE_GLL
        __syncthreads();
#endif
    }
    #undef QKV_STAGE

    const int rq = lane >> 4;
    #pragma unroll
    for (int rf = 0; rf < 4; ++rf) {
        #pragma unroll
        for (int r = 0; r < 4; ++r) {
            const int nl = wr * 64 + rf * 16 + rq * 4 + r;
            const float bv = bias[n0p + nl];
            ushort* dst = ct + (size_t)(n0p + nl) * M_TOTAL + m0 + wc * 64;
            #pragma unroll
            for (int cf = 0; cf < 4; ++cf) {
                union { _Float16 f; ushort u; } cvt;
                cvt.f = (_Float16)(acc[rf][cf][r] + bv);
                dst[cf * 16 + fr] = cvt.u;
            }
        }
    }
}

// ---------------------------------------------------------------------------
// Radix-16 FFT, paired sequences (r24-VALIDATED math/layout/swizzle).
// THIS ROUND: per-stage 3-buffer ILP -- all 48 loads issued up front
// (overlapped ds_read/global chains), 3 independent dft16 chains, SHARED
// twiddle (same angle for all buffers; same FP sequence -> bit-identical).
// Compiler previously serialized the buffers (VGPR 68); budget to 3
// waves/SIMD is 170 VGPR, so ~140 is safe.
// ---------------------------------------------------------------------------
__device__ __forceinline__ float2 cmul(float2 a, float2 b) {
    return {a.x*b.x - a.y*b.y, a.x*b.y + a.y*b.x};
}

// 4-byte-word LDS swizzle (r24-validated: conflicts = 0)
__device__ __forceinline__ int phys32(int p) {
    return p ^ ((p >> 4) & 15) ^ (((p >> 8) & 1) << 4);
}

__device__ __forceinline__ unsigned pk16(float2 v) {
    union { _Float16 f[2]; unsigned u; } c;
    c.f[0] = (_Float16)v.x; c.f[1] = (_Float16)v.y;
    return c.u;
}
__device__ __forceinline__ float2 upk16(unsigned u) {
    union { unsigned uu; _Float16 f[2]; } c; c.uu = u;
    return (float2){(float)c.f[0], (float)c.f[1]};
}

template<int DIR>
__device__ __forceinline__ void dft16(const float2* x, float2* X) {
    float2 t[16];
    #pragma unroll
    for (int n0 = 0; n0 < 4; ++n0) {
        float2 a = x[n0], b = x[n0+4], c = x[n0+8], d = x[n0+12];
        float2 s0 = {a.x+c.x, a.y+c.y}, s1 = {a.x-c.x, a.y-c.y};
        float2 s2 = {b.x+d.x, b.y+d.y}, s3 = {b.x-d.x, b.y-d.y};
        t[n0*4+0] = {s0.x+s2.x, s0.y+s2.y};
        t[n0*4+2] = {s0.x-s2.x, s0.y-s2.y};
        if (DIR < 0) {
            t[n0*4+1] = {s1.x+s3.y, s1.y-s3.x};
            t[n0*4+3] = {s1.x-s3.y, s1.y+s3.x};
        } else {
            t[n0*4+1] = {s1.x-s3.y, s1.y+s3.x};
            t[n0*4+3] = {s1.x+s3.y, s1.y-s3.x};
        }
    }
    const float C1 = 0.92387953251128674f;
    const float S1_ = 0.38268343236508978f;
    const float R2 = 0.70710678118654752f;
    #define TW(idx, cc_, ss_) t[idx] = cmul(t[idx], (float2){cc_, DIR*(ss_)})
    TW(1*4+1, C1, S1_);   TW(1*4+2, R2, R2);    TW(1*4+3, S1_, C1);
    TW(2*4+1, R2, R2);    TW(2*4+2, 0.f, 1.f);  TW(2*4+3, -R2, R2);
    TW(3*4+1, S1_, C1);   TW(3*4+2, -R2, R2);   TW(3*4+3, -C1, -S1_);
    #undef TW
    #pragma unroll
    for (int k0 = 0; k0 < 4; ++k0) {
        float2 a = t[0+k0], b = t[4+k0], c = t[8+k0], d = t[12+k0];
        float2 s0 = {a.x+c.x, a.y+c.y}, s1 = {a.x-c.x, a.y-c.y};
        float2 s2 = {b.x+d.x, b.y+d.y}, s3 = {b.x-d.x, b.y-d.y};
        X[k0+0]  = {s0.x+s2.x, s0.y+s2.y};
        X[k0+8]  = {s0.x-s2.x, s0.y-s2.y};
        if (DIR < 0) {
            X[k0+4]  = {s1.x+s3.y, s1.y-s3.x};
            X[k0+12] = {s1.x-s3.y, s1.y+s3.x};
        } else {
            X[k0+4]  = {s1.x-s3.y, s1.y+s3.x};
            X[k0+12] = {s1.x+s3.y, s1.y-s3.x};
        }
    }
}

__device__ __forceinline__ void twiddle_apply(float2* y, float ang) {
    float s, c;
    __sincosf(ang, &s, &c);
    const float2 base = {c, s};
    float2 w = base;
    #pragma unroll
    for (int u = 1; u < 16; ++u) {
        y[u] = cmul(y[u], w);
        w = cmul(w, base);
    }
}

// shared-angle twiddle for 3 buffers: same FP sequence for w as
// twiddle_apply, applied to each buffer (bit-identical per-element math).
__device__ __forceinline__ void twiddle_apply3(float2* y0, float2* y1,
                                               float2* y2, float ang) {
    float s, c;
    __sincosf(ang, &s, &c);
    const float2 base = {c, s};
    float2 w = base;
    #pragma unroll
    for (int u = 1; u < 16; ++u) {
        y0[u] = cmul(y0[u], w);
        y1[u] = cmul(y1[u], w);
        y2[u] = cmul(y2[u], w);
        w = cmul(w, base);
    }
}

__global__ __launch_bounds__(256) void fft_attn_kernel5(
    const ushort* __restrict__ qt, const ushort* __restrict__ kt,
    const ushort* __restrict__ vt, ushort* __restrict__ ot16)
{
    __shared__ unsigned zA[3][FFT_N];   // Z1, Z2, V12/H' packed fp16 (48 KiB)

    const int tid = threadIdx.x;
    const int bid = blockIdx.x;          // [0, 2048)
    const int n   = bid >> 1;
    const int bp  = bid & 1;

    const size_t off0 = (size_t)n * M_TOTAL + (size_t)(2 * bp) * SEQ;
    const size_t off1 = off0 + SEQ;
    const _Float16* q0 = (const _Float16*)qt + off0;
    const _Float16* k0 = (const _Float16*)kt + off0;
    const _Float16* q1 = (const _Float16*)qt + off1;
    const _Float16* k1 = (const _Float16*)kt + off1;
    const _Float16* v0 = (const _Float16*)vt + off0;
    const _Float16* v1 = (const _Float16*)vt + off1;
    _Float16* o0 = (_Float16*)ot16 + off0;
    _Float16* o1 = (_Float16*)ot16 + off1;

    // ---- forward stage 1 (stride 256): ALL loads first, 3 dft16, shared tw
    {
        float2 x0[16], x1[16], x2[16];
        #pragma unroll
        for (int r = 0; r < 16; ++r) {
            x0[r] = { (float)q0[tid + 256*r], (float)k0[tid + 256*r] };
            x1[r] = { (float)q1[tid + 256*r], (float)k1[tid + 256*r] };
            x2[r] = { (float)v0[tid + 256*r], (float)v1[tid + 256*r] };
        }
        float2 y0[16], y1[16], y2[16];
        dft16<-1>(x0, y0);
        dft16<-1>(x1, y1);
        dft16<-1>(x2, y2);
        twiddle_apply3(y0, y1, y2, -PI2 * (float)tid / 4096.f);
        #pragma unroll
        for (int u = 0; u < 16; ++u) {
            const int pp = phys32(tid + 256*u);
            zA[0][pp] = pk16(y0[u]);
            zA[1][pp] = pk16(y1[u]);
            zA[2][pp] = pk16(y2[u]);
        }
    }
    __syncthreads();
    // ---- forward stage 2 (stride 16): batched loads, 3 dft16, shared tw
    {
        const int blk = tid >> 4, a = tid & 15;
        const int base = 256*blk + a;
        float2 x0[16], x1[16], x2[16];
        #pragma unroll
        for (int c = 0; c < 16; ++c) {
            const int pp = phys32(base + 16*c);
            x0[c] = upk16(zA[0][pp]);
            x1[c] = upk16(zA[1][pp]);
            x2[c] = upk16(zA[2][pp]);
        }
        float2 y0[16], y1[16], y2[16];
        dft16<-1>(x0, y0);
        dft16<-1>(x1, y1);
        dft16<-1>(x2, y2);
        twiddle_apply3(y0, y1, y2, -PI2 * (float)a / 256.f);
        #pragma unroll
        for (int c = 0; c < 16; ++c) {
            const int pp = phys32(base + 16*c);
            zA[0][pp] = pk16(y0[c]);
            zA[1][pp] = pk16(y1[c]);
            zA[2][pp] = pk16(y2[c]);
        }
    }
    __syncthreads();
    // ---- forward stage 3 (contiguous 16): batched, no twiddle
    {
        const int base = 256*(tid >> 4) + 16*(tid & 15);
        float2 x0[16], x1[16], x2[16];
        #pragma unroll
        for (int e = 0; e < 16; ++e) {
            const int pp = phys32(base + e);
            x0[e] = upk16(zA[0][pp]);
            x1[e] = upk16(zA[1][pp]);
            x2[e] = upk16(zA[2][pp]);
        }
        float2 y0[16], y1[16], y2[16];
        dft16<-1>(x0, y0);
        dft16<-1>(x1, y1);
        dft16<-1>(x2, y2);
        #pragma unroll
        for (int e = 0; e < 16; ++e) {
            const int pp = phys32(base + e);
            zA[0][pp] = pk16(y0[e]);
            zA[1][pp] = pk16(y1[e]);
            zA[2][pp] = pk16(y2[e]);
        }
    }
    __syncthreads();
    // ---- pointwise (r22/r24-validated formula): H' = (F1 + i*F2)/4096
    float2 H[16];
    #pragma unroll
    for (int it = 0; it < 16; ++it) {
        const int p  = tid + it * 256;
        const int j  = ((p & 15) << 8) | (p & 0xF0) | (p >> 8);
        const int jn = (FFT_N - j) & (FFT_N - 1);
        const int pn = ((jn & 15) << 8) | (jn & 0xF0) | (jn >> 8);
        const float2 Vj = upk16(zA[2][phys32(p)]);
        const float2 Vn = upk16(zA[2][phys32(pn)]);
        const float2 V1 = { 0.5f*(Vj.x + Vn.x),  0.5f*(Vj.y - Vn.y) };
        const float2 V2 = { 0.5f*(Vj.y + Vn.y), -0.5f*(Vj.x - Vn.x) };
        float2 F1, F2;
        {
            const float2 Zj = upk16(zA[0][phys32(p)]);
            const float2 Zn = upk16(zA[0][phys32(pn)]);
            const float2 Q = { 0.5f*(Zj.x + Zn.x),  0.5f*(Zj.y - Zn.y) };
            const float2 K = { 0.5f*(Zj.y + Zn.y), -0.5f*(Zj.x - Zn.x) };
            const float2 G = { Q.x*K.x + Q.y*K.y, Q.y*K.x - Q.x*K.y };
            F1 = { G.x*V1.x - G.y*V1.y, G.x*V1.y + G.y*V1.x };
        }
        {
            const float2 Zj = upk16(zA[1][phys32(p)]);
            const float2 Zn = upk16(zA[1][phys32(pn)]);
            const float2 Q = { 0.5f*(Zj.x + Zn.x),  0.5f*(Zj.y - Zn.y) };
            const float2 K = { 0.5f*(Zj.y + Zn.y), -0.5f*(Zj.x - Zn.x) };
            const float2 G = { Q.x*K.x + Q.y*K.y, Q.y*K.x - Q.x*K.y };
            F2 = { G.x*V2.x - G.y*V2.y, G.x*V2.y + G.y*V2.x };
        }
        const float inv_n = 1.0f / 4096.f;
        H[it] = { (F1.x - F2.y) * inv_n, (F1.y + F2.x) * inv_n };   // (F1 + i*F2)/N
    }
    __syncthreads();          // all reads of zA[2] complete before overwrite
    #pragma unroll
    for (int it = 0; it < 16; ++it)
        zA[2][phys32(tid + it * 256)] = pk16(H[it]);
    __syncthreads();
    // ---- inverse stage A (contiguous 16), buffer zA[2]
    {
        const int base = 256*(tid >> 4) + 16*(tid & 15);
        float2 x[16], y[16];
        #pragma unroll
        for (int d = 0; d < 16; ++d) x[d] = upk16(zA[2][phys32(base + d)]);
        dft16<1>(x, y);
        #pragma unroll
        for (int p0 = 0; p0 < 16; ++p0) zA[2][phys32(base + p0)] = pk16(y[p0]);
    }
    __syncthreads();
    // ---- inverse stage B (stride 16), input twiddle
    {
        const int blk = tid >> 4, p0 = tid & 15;
        const int base = 256*blk + p0;
        float2 x[16], y[16];
        #pragma unroll
        for (int c = 0; c < 16; ++c) x[c] = upk16(zA[2][phys32(base + 16*c)]);
        twiddle_apply(x, PI2 * (float)p0 / 256.f);
        dft16<1>(x, y);
        #pragma unroll
        for (int p1 = 0; p1 < 16; ++p1) zA[2][phys32(base + 16*p1)] = pk16(y[p1]);
    }
    __syncthreads();
    // ---- inverse stage C (stride 256), twiddle, fp16 dual store (scale 1/8)
    {
        const int qq = tid;
        float2 x[16], y[16];
        #pragma unroll
        for (int t = 0; t < 16; ++t) x[t] = upk16(zA[2][phys32(qq + 256*t)]);
        twiddle_apply(x, PI2 * (float)qq / 4096.f);
        dft16<1>(x, y);
        const float scale = 0.125f;   // 1/sqrt(64); 1/N already folded into H'
        #pragma unroll
        for (int p2 = 0; p2 < 16; ++p2) {
            o0[qq + 256*p2] = (_Float16)(y[p2].x * scale);
            o1[qq + 256*p2] = (_Float16)(y[p2].y * scale);
        }
    }
}

// ---------------------------------------------------------------------------
// Transpose (fp16 in, fp16 out): ot16 [n][m] -> oth [m][k=n]  (r22-validated)
// ---------------------------------------------------------------------------
__global__ __launch_bounds__(256) void transpose_cvt_kernel(
    const ushort* __restrict__ ot, ushort* __restrict__ oth)
{
    __shared__ float tile[64][65];
    const int tid = threadIdx.x;
    const int m0  = blockIdx.x * 64;
    const int n0  = blockIdx.y * 64;
    const int r   = tid >> 4;
    const int c   = tid & 15;

    #pragma unroll
    for (int rr = 0; rr < 4; ++rr) {
        const int nl = r + rr * 16;
        ushort4 v = *(const ushort4*)(ot + (size_t)(n0 + nl) * M_TOTAL + m0 + c * 4);
        union { ushort u; _Float16 f; } cv;
        cv.u = v.x; tile[nl][c * 4 + 0] = (float)cv.f;
        cv.u = v.y; tile[nl][c * 4 + 1] = (float)cv.f;
        cv.u = v.z; tile[nl][c * 4 + 2] = (float)cv.f;
        cv.u = v.w; tile[nl][c * 4 + 3] = (float)cv.f;
    }
    __syncthreads();
    #pragma unroll
    for (int rr = 0; rr < 4; ++rr) {
        const int ml = r + rr * 16;
        ushort4 hh;
        union { _Float16 f; ushort u; } cv;
        cv.f = (_Float16)tile[c * 4 + 0][ml]; hh.x = cv.u;
        cv.f = (_Float16)tile[c * 4 + 1][ml]; hh.y = cv.u;
        cv.f = (_Float16)tile[c * 4 + 2][ml]; hh.z = cv.u;
        cv.f = (_Float16)tile[c * 4 + 3][ml]; hh.w = cv.u;
        *(ushort4*)(oth + (size_t)(m0 + ml) * HIDDEN + n0 + c * 4) = hh;
    }
}

// ---------------------------------------------------------------------------
// Output GEMM (r20/r22/r24-VALIDATED, byte-identical)
// ---------------------------------------------------------------------------
__global__ __launch_bounds__(1024, 1) void gemm_out_mfma8(
    const ushort* __restrict__ oth, const ushort* __restrict__ woh,
    const float* __restrict__ bo, float* __restrict__ out)
{
    __shared__ ushort Ah[3][8192];
    __shared__ ushort Bh[3][8192];

    const int tid  = threadIdx.x;
    const int lane = tid & 63;
    const int wid  = tid >> 6;
    const int wr   = wid >> 2;
    const int wc   = wid & 3;
    const int m0   = blockIdx.x * 256;
    const int n0   = blockIdx.y * 256;

    const int row = tid >> 2;
    const int chS = (tid & 3) ^ ((row >> 1) & 3);

    const int fr = lane & 15;
    const int fc = lane >> 4;
    const int cc = (fc ^ ((fr >> 1) & 3)) * 8;

    f32x4 acc[4][4];
    #pragma unroll
    for (int rf = 0; rf < 4; ++rf)
        #pragma unroll
        for (int cf = 0; cf < 4; ++cf)
            acc[rf][cf] = (f32x4){0.f, 0.f, 0.f, 0.f};

#if HAVE_GLL
    #define OUT_STAGE(K0, SLOT) {                                                  \
        const size_t ga = (size_t)(m0 + row) * HIDDEN + (K0) + (size_t)chS * 8;    \
        const size_t gb = (size_t)(n0 + row) * HIDDEN + (K0) + (size_t)chS * 8;    \
        gload16(oth + ga, &Ah[SLOT][(size_t)tid * 8]);                             \
        gload16(woh + gb, &Bh[SLOT][(size_t)tid * 8]);                             \
    }
#else
    #define OUT_STAGE(K0, SLOT) {                                                  \
        const size_t ga = (size_t)(m0 + row) * HIDDEN + (K0) + (size_t)chS * 8;    \
        const size_t gb = (size_t)(n0 + row) * HIDDEN + (K0) + (size_t)chS * 8;    \
        *(f16x8*)&Ah[SLOT][(size_t)tid * 8] = *(const f16x8*)(oth + ga);           \
        *(f16x8*)&Bh[SLOT][(size_t)tid * 8] = *(const f16x8*)(woh + gb);           \
    }
#endif

    OUT_STAGE(0, 0);
    OUT_STAGE(32, 1);

    for (int ks = 0; ks < 32; ++ks) {
        const int slot = ks % 3;
#if HAVE_GLL
        if (ks == 31) { asm volatile("s_waitcnt vmcnt(0)" ::: "memory"); }
        else          { asm volatile("s_waitcnt vmcnt(2)" ::: "memory"); }
        __builtin_amdgcn_s_barrier();
        asm volatile("" ::: "memory");
#else
        __syncthreads();
#endif
        {
            const ushort* pAh = Ah[slot];
            const ushort* pBh = Bh[slot];
            f16x8 a_h[4], b_h[4];
            #pragma unroll
            for (int rf = 0; rf < 4; ++rf) {
                const int R = wr * 64 + rf * 16 + fr;
                a_h[rf] = *(const f16x8*)(pAh + R * 32 + cc);
            }
            #pragma unroll
            for (int cf = 0; cf < 4; ++cf) {
                const int R = wc * 64 + cf * 16 + fr;
                b_h[cf] = *(const f16x8*)(pBh + R * 32 + cc);
            }
            #pragma unroll
            for (int rf = 0; rf < 4; ++rf)
                #pragma unroll
                for (int cf = 0; cf < 4; ++cf)
                    acc[rf][cf] = __builtin_amdgcn_mfma_f32_16x16x32_f16(a_h[rf], b_h[cf], acc[rf][cf], 0, 0, 0);
        }
        if (ks + 2 < 32) { OUT_STAGE((ks + 2) * 32, (ks + 2) % 3); }
#if !HAVE_GLL
        __syncthreads();
#endif
    }
    #undef OUT_STAGE

    const int rq = lane >> 4;
    float bo_v[4];
    #pragma unroll
    for (int cf = 0; cf < 4; ++cf) bo_v[cf] = bo[n0 + wc * 64 + cf * 16 + fr];
    #pragma unroll
    for (int rf = 0; rf < 4; ++rf) {
        #pragma unroll
        for (int r = 0; r < 4; ++r) {
            const int ml = wr * 64 + rf * 16 + rq * 4 + r;
            float* dst = out + (size_t)(m0 + ml) * HIDDEN + n0 + wc * 64;
            #pragma unroll
            for (int cf = 0; cf < 4; ++cf)
                dst[cf * 16 + fr] = acc[rf][cf][r] + bo_v[cf];
        }
    }
}

// ---------------------------------------------------------------------------
// Buffers (ws = proven 201.3 MB; peak use 136.3 MB):
//   ws[0..100.66M):        qkvt fp16 [3][1024][16384]
//   ws[100.66..134.2M):    ot16 fp16 [1024][16384]
//   ws[134.2..136.3M):     woh fp16 [1024][1024]
//   After fft: oth (33.5 MB) aliases the dead qkvt region.
//   d_out stash: xh 33.55 + wh 6.29 = 39.8 MB < 67.1; dead before gemm_out.
// ---------------------------------------------------------------------------
extern "C" void kernel_launch(void* const* d_in, const int* in_sizes, int n_in,
                              void* d_out, int out_size, void* d_ws, size_t ws_size,
                              hipStream_t stream)
{
    const float* x  = (const float*)d_in[0];
    const float* Wq = (const float*)d_in[1];
    const float* bq = (const float*)d_in[2];
    const float* Wk = (const float*)d_in[3];
    const float* bk = (const float*)d_in[4];
    const float* Wv = (const float*)d_in[5];
    const float* bv = (const float*)d_in[6];
    const float* Wo = (const float*)d_in[7];
    const float* bo = (const float*)d_in[8];
    float* out = (float*)d_out;

    const size_t plane = (size_t)HIDDEN * M_TOTAL;   // 16.78M elements
    ushort* qkvt = (ushort*)d_ws;                    // fp16 [3][1024][16384]
    ushort* qt16 = qkvt;
    ushort* kt16 = qkvt + plane;
    ushort* vt16 = qkvt + 2 * plane;
    ushort* ot16 = qkvt + 3 * plane;                 // fp16 [1024][16384]
    ushort* woh  = ot16 + plane;                     // fp16 [1024][1024]

    // post-fft stash aliases dead qkvt region
    ushort* oth = qkvt;                              // [16384][1024] fp16

    // fp16 operand stash in d_out (dead before gemm_out writes d_out)
    ushort* xh  = (ushort*)d_out;                    // [16384][1024]
    ushort* wh  = xh + plane;                        // stacked [3072][1024]

    // pre-passes
    cvt16_kernel<<<(unsigned)(plane / 2048), 256, 0, stream>>>(x, xh);
    cvtW_kernel<<<dim3((unsigned)(WSZ / 2048), 4), 256, 0, stream>>>(
        Wq, Wk, Wv, Wo, wh, woh);

    // QKV projections
    gemm_qkv_mfma8<<<dim3(M_TOTAL / 256, 12), 1024, 0, stream>>>(
        xh, wh, bq, bk, bv, qkvt);

    // FFT attention: 2 seqs/block, 48 KiB LDS, 3-buffer ILP stages
    fft_attn_kernel5<<<dim3(HIDDEN * BATCH / 2), 256, 0, stream>>>(
        qt16, kt16, vt16, ot16);

    // transpose ot16 -> oth [m][k]
    transpose_cvt_kernel<<<dim3(M_TOTAL / 64, HIDDEN / 64), 256, 0, stream>>>(
        ot16, oth);

    // output projection
    gemm_out_mfma8<<<dim3(M_TOTAL / 256, HIDDEN / 256), 1024, 0, stream>>>(
        oth, woh, bo, out);
}

// Round 26
// 240.725 us; speedup vs baseline: 1.1051x; 1.0076x over previous
//
#include <hip/hip_runtime.h>
#include <hip/hip_bf16.h>
#include <math.h>

#define HIDDEN   1024
#define HEADS    16
#define HEAD_DIM 64
#define BATCH    4
#define SEQ      4096
#define M_TOTAL  (BATCH * SEQ)          // 16384
#define FFT_N    4096
#define WSZ      ((size_t)HIDDEN * HIDDEN)
#define PI2      6.28318530717958647692f

typedef _Float16 f16x8 __attribute__((ext_vector_type(8)));   // 8 fp16 = 4 VGPR (MFMA A/B frag)
typedef float    f32x4 __attribute__((ext_vector_type(4)));   // MFMA C/D frag

#if defined(__has_builtin)
#if __has_builtin(__builtin_amdgcn_global_load_lds)
#define HAVE_GLL 1
#else
#define HAVE_GLL 0
#endif
#else
#define HAVE_GLL 0
#endif

#if HAVE_GLL
// async global->LDS, 16B/lane. dest = wave-uniform base + lane*16 (linear in slot).
__device__ __forceinline__ void gload16(const void* g, void* l) {
    __builtin_amdgcn_global_load_lds(
        (const __attribute__((address_space(1))) unsigned int*)g,
        (__attribute__((address_space(3))) unsigned int*)l,
        16, 0, 0);
}
#endif

__device__ __forceinline__ void cvt8_f16(float4 v0, float4 v1,
                                         ushort* __restrict__ d) {
    const float vv[8] = {v0.x, v0.y, v0.z, v0.w, v1.x, v1.y, v1.z, v1.w};
    f16x8 hv;
    #pragma unroll
    for (int e = 0; e < 8; ++e) hv[e] = (_Float16)vv[e];
    *(f16x8*)d = hv;
}

// ---------------------------------------------------------------------------
// Pre-pass kernels (r20/r22-validated)
// ---------------------------------------------------------------------------
__global__ __launch_bounds__(256) void cvt16_kernel(
    const float* __restrict__ src, ushort* __restrict__ h)
{
    const size_t i = ((size_t)blockIdx.x * 256 + threadIdx.x) * 8;
    float4 v0 = *(const float4*)(src + i);
    float4 v1 = *(const float4*)(src + i + 4);
    cvt8_f16(v0, v1, h + i);
}

__global__ __launch_bounds__(256) void cvtW_kernel(
    const float* __restrict__ Wq, const float* __restrict__ Wk,
    const float* __restrict__ Wv, const float* __restrict__ Wo,
    ushort* __restrict__ wh, ushort* __restrict__ woh)
{
    const int p = blockIdx.y;                 // 0=q 1=k 2=v 3=o
    const size_t i = ((size_t)blockIdx.x * 256 + threadIdx.x) * 8;
    const float* __restrict__ src = (p == 0) ? Wq : (p == 1 ? Wk : (p == 2 ? Wv : Wo));
    ushort* __restrict__ dst = (p < 3) ? (wh + (size_t)p * WSZ) : woh;
    float4 v0 = *(const float4*)(src + i);
    float4 v1 = *(const float4*)(src + i + 4);
    cvt8_f16(v0, v1, dst + i);
}

// ---------------------------------------------------------------------------
// QKV GEMM (r20/r22/r24-VALIDATED, byte-identical)
// ---------------------------------------------------------------------------
__global__ __launch_bounds__(1024, 1) void gemm_qkv_mfma8(
    const ushort* __restrict__ xh, const ushort* __restrict__ wh,
    const float* __restrict__ bq, const float* __restrict__ bk,
    const float* __restrict__ bv,
    ushort* __restrict__ qkvt)
{
    __shared__ ushort Ah[3][8192];
    __shared__ ushort Bh[3][8192];

    const int tid  = threadIdx.x;
    const int lane = tid & 63;
    const int wid  = tid >> 6;
    const int wr   = wid >> 2;
    const int wc   = wid & 3;
    const int m0   = blockIdx.x * 256;
    const int ng0  = blockIdx.y * 256;
    const int p    = ng0 >> 10;
    const int n0p  = ng0 & 1023;

    const float* __restrict__ bias = (p == 0) ? bq : (p == 1 ? bk : bv);
    ushort* __restrict__ ct = qkvt + (size_t)p * HIDDEN * M_TOTAL;

    const int row = tid >> 2;
    const int chS = (tid & 3) ^ ((row >> 1) & 3);

    const int fr = lane & 15;
    const int fc = lane >> 4;
    const int cc = (fc ^ ((fr >> 1) & 3)) * 8;

    f32x4 acc[4][4];
    #pragma unroll
    for (int rf = 0; rf < 4; ++rf)
        #pragma unroll
        for (int cf = 0; cf < 4; ++cf)
            acc[rf][cf] = (f32x4){0.f, 0.f, 0.f, 0.f};

#if HAVE_GLL
    #define QKV_STAGE(K0, SLOT) {                                                  \
        const size_t gw = (size_t)(ng0 + row) * HIDDEN + (K0) + (size_t)chS * 8;   \
        const size_t gx = (size_t)(m0 + row) * HIDDEN + (K0) + (size_t)chS * 8;    \
        gload16(wh + gw, &Ah[SLOT][(size_t)tid * 8]);                              \
        gload16(xh + gx, &Bh[SLOT][(size_t)tid * 8]);                              \
    }
#else
    #define QKV_STAGE(K0, SLOT) {                                                  \
        const size_t gw = (size_t)(ng0 + row) * HIDDEN + (K0) + (size_t)chS * 8;   \
        const size_t gx = (size_t)(m0 + row) * HIDDEN + (K0) + (size_t)chS * 8;    \
        *(f16x8*)&Ah[SLOT][(size_t)tid * 8] = *(const f16x8*)(wh + gw);            \
        *(f16x8*)&Bh[SLOT][(size_t)tid * 8] = *(const f16x8*)(xh + gx);            \
    }
#endif

    QKV_STAGE(0, 0);
    QKV_STAGE(32, 1);

    for (int ks = 0; ks < 32; ++ks) {
        const int slot = ks % 3;
#if HAVE_GLL
        if (ks == 31) { asm volatile("s_waitcnt vmcnt(0)" ::: "memory"); }
        else          { asm volatile("s_waitcnt vmcnt(2)" ::: "memory"); }
        __builtin_amdgcn_s_barrier();
        asm volatile("" ::: "memory");
#else
        __syncthreads();
#endif
        {
            const ushort* pAh = Ah[slot];
            const ushort* pBh = Bh[slot];
            f16x8 a_h[4], b_h[4];
            #pragma unroll
            for (int rf = 0; rf < 4; ++rf) {
                const int R = wr * 64 + rf * 16 + fr;
                a_h[rf] = *(const f16x8*)(pAh + R * 32 + cc);
            }
            #pragma unroll
            for (int cf = 0; cf < 4; ++cf) {
                const int R = wc * 64 + cf * 16 + fr;
                b_h[cf] = *(const f16x8*)(pBh + R * 32 + cc);
            }
            #pragma unroll
            for (int rf = 0; rf < 4; ++rf)
                #pragma unroll
                for (int cf = 0; cf < 4; ++cf)
                    acc[rf][cf] = __builtin_amdgcn_mfma_f32_16x16x32_f16(a_h[rf], b_h[cf], acc[rf][cf], 0, 0, 0);
        }
        if (ks + 2 < 32) { QKV_STAGE((ks + 2) * 32, (ks + 2) % 3); }
#if !HAVE_GLL
        __syncthreads();
#endif
    }
    #undef QKV_STAGE

    const int rq = lane >> 4;
    #pragma unroll
    for (int rf = 0; rf < 4; ++rf) {
        #pragma unroll
        for (int r = 0; r < 4; ++r) {
            const int nl = wr * 64 + rf * 16 + rq * 4 + r;
            const float bv = bias[n0p + nl];
            ushort* dst = ct + (size_t)(n0p + nl) * M_TOTAL + m0 + wc * 64;
            #pragma unroll
            for (int cf = 0; cf < 4; ++cf) {
                union { _Float16 f; ushort u; } cvt;
                cvt.f = (_Float16)(acc[rf][cf][r] + bv);
                dst[cf * 16 + fr] = cvt.u;
            }
        }
    }
}

// ---------------------------------------------------------------------------
// Radix-16 FFT, paired sequences (r24/r25-VALIDATED math/layout/swizzle).
// THIS ROUND: pointwise FUSED with inverse stage A in registers.
// Inverse stage A consumes contiguous-16 blocks base=256*(tid>>4)+16*(tid&15);
// the pointwise now enumerates exactly those positions (bijective cover, same
// per-element formula), computes H'[16] in regs, runs dft16<+1> immediately,
// then ONE barrier (drain all zA reads) before writing stage-A output.
// Removes: 16 ds_write + 16 ds_read + 32 pk/upk + 1 barrier per thread, and
// one fp16 roundtrip of H' (precision net-positive).
// ---------------------------------------------------------------------------
__device__ __forceinline__ float2 cmul(float2 a, float2 b) {
    return {a.x*b.x - a.y*b.y, a.x*b.y + a.y*b.x};
}

// 4-byte-word LDS swizzle (r24-validated: conflicts = 0)
__device__ __forceinline__ int phys32(int p) {
    return p ^ ((p >> 4) & 15) ^ (((p >> 8) & 1) << 4);
}

__device__ __forceinline__ unsigned pk16(float2 v) {
    union { _Float16 f[2]; unsigned u; } c;
    c.f[0] = (_Float16)v.x; c.f[1] = (_Float16)v.y;
    return c.u;
}
__device__ __forceinline__ float2 upk16(unsigned u) {
    union { unsigned uu; _Float16 f[2]; } c; c.uu = u;
    return (float2){(float)c.f[0], (float)c.f[1]};
}

template<int DIR>
__device__ __forceinline__ void dft16(const float2* x, float2* X) {
    float2 t[16];
    #pragma unroll
    for (int n0 = 0; n0 < 4; ++n0) {
        float2 a = x[n0], b = x[n0+4], c = x[n0+8], d = x[n0+12];
        float2 s0 = {a.x+c.x, a.y+c.y}, s1 = {a.x-c.x, a.y-c.y};
        float2 s2 = {b.x+d.x, b.y+d.y}, s3 = {b.x-d.x, b.y-d.y};
        t[n0*4+0] = {s0.x+s2.x, s0.y+s2.y};
        t[n0*4+2] = {s0.x-s2.x, s0.y-s2.y};
        if (DIR < 0) {
            t[n0*4+1] = {s1.x+s3.y, s1.y-s3.x};
            t[n0*4+3] = {s1.x-s3.y, s1.y+s3.x};
        } else {
            t[n0*4+1] = {s1.x-s3.y, s1.y+s3.x};
            t[n0*4+3] = {s1.x+s3.y, s1.y-s3.x};
        }
    }
    const float C1 = 0.92387953251128674f;
    const float S1_ = 0.38268343236508978f;
    const float R2 = 0.70710678118654752f;
    #define TW(idx, cc_, ss_) t[idx] = cmul(t[idx], (float2){cc_, DIR*(ss_)})
    TW(1*4+1, C1, S1_);   TW(1*4+2, R2, R2);    TW(1*4+3, S1_, C1);
    TW(2*4+1, R2, R2);    TW(2*4+2, 0.f, 1.f);  TW(2*4+3, -R2, R2);
    TW(3*4+1, S1_, C1);   TW(3*4+2, -R2, R2);   TW(3*4+3, -C1, -S1_);
    #undef TW
    #pragma unroll
    for (int k0 = 0; k0 < 4; ++k0) {
        float2 a = t[0+k0], b = t[4+k0], c = t[8+k0], d = t[12+k0];
        float2 s0 = {a.x+c.x, a.y+c.y}, s1 = {a.x-c.x, a.y-c.y};
        float2 s2 = {b.x+d.x, b.y+d.y}, s3 = {b.x-d.x, b.y-d.y};
        X[k0+0]  = {s0.x+s2.x, s0.y+s2.y};
        X[k0+8]  = {s0.x-s2.x, s0.y-s2.y};
        if (DIR < 0) {
            X[k0+4]  = {s1.x+s3.y, s1.y-s3.x};
            X[k0+12] = {s1.x-s3.y, s1.y+s3.x};
        } else {
            X[k0+4]  = {s1.x-s3.y, s1.y+s3.x};
            X[k0+12] = {s1.x+s3.y, s1.y-s3.x};
        }
    }
}

__device__ __forceinline__ void twiddle_apply(float2* y, float ang) {
    float s, c;
    __sincosf(ang, &s, &c);
    const float2 base = {c, s};
    float2 w = base;
    #pragma unroll
    for (int u = 1; u < 16; ++u) {
        y[u] = cmul(y[u], w);
        w = cmul(w, base);
    }
}

// shared-angle twiddle for 3 buffers (r25-validated)
__device__ __forceinline__ void twiddle_apply3(float2* y0, float2* y1,
                                               float2* y2, float ang) {
    float s, c;
    __sincosf(ang, &s, &c);
    const float2 base = {c, s};
    float2 w = base;
    #pragma unroll
    for (int u = 1; u < 16; ++u) {
        y0[u] = cmul(y0[u], w);
        y1[u] = cmul(y1[u], w);
        y2[u] = cmul(y2[u], w);
        w = cmul(w, base);
    }
}

__global__ __launch_bounds__(256) void fft_attn_kernel6(
    const ushort* __restrict__ qt, const ushort* __restrict__ kt,
    const ushort* __restrict__ vt, ushort* __restrict__ ot16)
{
    __shared__ unsigned zA[3][FFT_N];   // Z1, Z2, V12 packed fp16 (48 KiB)

    const int tid = threadIdx.x;
    const int bid = blockIdx.x;          // [0, 2048)
    const int n   = bid >> 1;
    const int bp  = bid & 1;

    const size_t off0 = (size_t)n * M_TOTAL + (size_t)(2 * bp) * SEQ;
    const size_t off1 = off0 + SEQ;
    const _Float16* q0 = (const _Float16*)qt + off0;
    const _Float16* k0 = (const _Float16*)kt + off0;
    const _Float16* q1 = (const _Float16*)qt + off1;
    const _Float16* k1 = (const _Float16*)kt + off1;
    const _Float16* v0 = (const _Float16*)vt + off0;
    const _Float16* v1 = (const _Float16*)vt + off1;
    _Float16* o0 = (_Float16*)ot16 + off0;
    _Float16* o1 = (_Float16*)ot16 + off1;

    // ---- forward stage 1 (stride 256): batched loads, 3 dft16, shared tw
    {
        float2 x0[16], x1[16], x2[16];
        #pragma unroll
        for (int r = 0; r < 16; ++r) {
            x0[r] = { (float)q0[tid + 256*r], (float)k0[tid + 256*r] };
            x1[r] = { (float)q1[tid + 256*r], (float)k1[tid + 256*r] };
            x2[r] = { (float)v0[tid + 256*r], (float)v1[tid + 256*r] };
        }
        float2 y0[16], y1[16], y2[16];
        dft16<-1>(x0, y0);
        dft16<-1>(x1, y1);
        dft16<-1>(x2, y2);
        twiddle_apply3(y0, y1, y2, -PI2 * (float)tid / 4096.f);
        #pragma unroll
        for (int u = 0; u < 16; ++u) {
            const int pp = phys32(tid + 256*u);
            zA[0][pp] = pk16(y0[u]);
            zA[1][pp] = pk16(y1[u]);
            zA[2][pp] = pk16(y2[u]);
        }
    }
    __syncthreads();
    // ---- forward stage 2 (stride 16)
    {
        const int blk = tid >> 4, a = tid & 15;
        const int base = 256*blk + a;
        float2 x0[16], x1[16], x2[16];
        #pragma unroll
        for (int c = 0; c < 16; ++c) {
            const int pp = phys32(base + 16*c);
            x0[c] = upk16(zA[0][pp]);
            x1[c] = upk16(zA[1][pp]);
            x2[c] = upk16(zA[2][pp]);
        }
        float2 y0[16], y1[16], y2[16];
        dft16<-1>(x0, y0);
        dft16<-1>(x1, y1);
        dft16<-1>(x2, y2);
        twiddle_apply3(y0, y1, y2, -PI2 * (float)a / 256.f);
        #pragma unroll
        for (int c = 0; c < 16; ++c) {
            const int pp = phys32(base + 16*c);
            zA[0][pp] = pk16(y0[c]);
            zA[1][pp] = pk16(y1[c]);
            zA[2][pp] = pk16(y2[c]);
        }
    }
    __syncthreads();
    // ---- forward stage 3 (contiguous 16)
    {
        const int base = 256*(tid >> 4) + 16*(tid & 15);
        float2 x0[16], x1[16], x2[16];
        #pragma unroll
        for (int e = 0; e < 16; ++e) {
            const int pp = phys32(base + e);
            x0[e] = upk16(zA[0][pp]);
            x1[e] = upk16(zA[1][pp]);
            x2[e] = upk16(zA[2][pp]);
        }
        float2 y0[16], y1[16], y2[16];
        dft16<-1>(x0, y0);
        dft16<-1>(x1, y1);
        dft16<-1>(x2, y2);
        #pragma unroll
        for (int e = 0; e < 16; ++e) {
            const int pp = phys32(base + e);
            zA[0][pp] = pk16(y0[e]);
            zA[1][pp] = pk16(y1[e]);
            zA[2][pp] = pk16(y2[e]);
        }
    }
    __syncthreads();
    // ---- FUSED pointwise + inverse stage A (contig-16 positions, in regs)
    {
        const int base = 256*(tid >> 4) + 16*(tid & 15);
        float2 Hreg[16];
        #pragma unroll
        for (int e = 0; e < 16; ++e) {
            const int p  = base + e;
            const int j  = ((p & 15) << 8) | (p & 0xF0) | (p >> 8);
            const int jn = (FFT_N - j) & (FFT_N - 1);
            const int pn = ((jn & 15) << 8) | (jn & 0xF0) | (jn >> 8);
            const float2 Vj = upk16(zA[2][phys32(p)]);
            const float2 Vn = upk16(zA[2][phys32(pn)]);
            const float2 V1 = { 0.5f*(Vj.x + Vn.x),  0.5f*(Vj.y - Vn.y) };
            const float2 V2 = { 0.5f*(Vj.y + Vn.y), -0.5f*(Vj.x - Vn.x) };
            float2 F1, F2;
            {
                const float2 Zj = upk16(zA[0][phys32(p)]);
                const float2 Zn = upk16(zA[0][phys32(pn)]);
                const float2 Q = { 0.5f*(Zj.x + Zn.x),  0.5f*(Zj.y - Zn.y) };
                const float2 K = { 0.5f*(Zj.y + Zn.y), -0.5f*(Zj.x - Zn.x) };
                const float2 G = { Q.x*K.x + Q.y*K.y, Q.y*K.x - Q.x*K.y };
                F1 = { G.x*V1.x - G.y*V1.y, G.x*V1.y + G.y*V1.x };
            }
            {
                const float2 Zj = upk16(zA[1][phys32(p)]);
                const float2 Zn = upk16(zA[1][phys32(pn)]);
                const float2 Q = { 0.5f*(Zj.x + Zn.x),  0.5f*(Zj.y - Zn.y) };
                const float2 K = { 0.5f*(Zj.y + Zn.y), -0.5f*(Zj.x - Zn.x) };
                const float2 G = { Q.x*K.x + Q.y*K.y, Q.y*K.x - Q.x*K.y };
                F2 = { G.x*V2.x - G.y*V2.y, G.x*V2.y + G.y*V2.x };
            }
            const float inv_n = 1.0f / 4096.f;
            Hreg[e] = { (F1.x - F2.y) * inv_n, (F1.y + F2.x) * inv_n };  // (F1+i*F2)/N
        }
        float2 yA[16];
        dft16<1>(Hreg, yA);          // inverse stage A directly on registers
        __syncthreads();             // all zA reads (any thread) complete
        #pragma unroll
        for (int e = 0; e < 16; ++e)
            zA[2][phys32(base + e)] = pk16(yA[e]);
    }
    __syncthreads();
    // ---- inverse stage B (stride 16), input twiddle
    {
        const int blk = tid >> 4, p0 = tid & 15;
        const int base = 256*blk + p0;
        float2 x[16], y[16];
        #pragma unroll
        for (int c = 0; c < 16; ++c) x[c] = upk16(zA[2][phys32(base + 16*c)]);
        twiddle_apply(x, PI2 * (float)p0 / 256.f);
        dft16<1>(x, y);
        #pragma unroll
        for (int p1 = 0; p1 < 16; ++p1) zA[2][phys32(base + 16*p1)] = pk16(y[p1]);
    }
    __syncthreads();
    // ---- inverse stage C (stride 256), twiddle, fp16 dual store (scale 1/8)
    {
        const int qq = tid;
        float2 x[16], y[16];
        #pragma unroll
        for (int t = 0; t < 16; ++t) x[t] = upk16(zA[2][phys32(qq + 256*t)]);
        twiddle_apply(x, PI2 * (float)qq / 4096.f);
        dft16<1>(x, y);
        const float scale = 0.125f;   // 1/sqrt(64); 1/N folded into H'
        #pragma unroll
        for (int p2 = 0; p2 < 16; ++p2) {
            o0[qq + 256*p2] = (_Float16)(y[p2].x * scale);
            o1[qq + 256*p2] = (_Float16)(y[p2].y * scale);
        }
    }
}

// ---------------------------------------------------------------------------
// Transpose (fp16 in, fp16 out): ot16 [n][m] -> oth [m][k=n]  (r22-validated)
// ---------------------------------------------------------------------------
__global__ __launch_bounds__(256) void transpose_cvt_kernel(
    const ushort* __restrict__ ot, ushort* __restrict__ oth)
{
    __shared__ float tile[64][65];
    const int tid = threadIdx.x;
    const int m0  = blockIdx.x * 64;
    const int n0  = blockIdx.y * 64;
    const int r   = tid >> 4;
    const int c   = tid & 15;

    #pragma unroll
    for (int rr = 0; rr < 4; ++rr) {
        const int nl = r + rr * 16;
        ushort4 v = *(const ushort4*)(ot + (size_t)(n0 + nl) * M_TOTAL + m0 + c * 4);
        union { ushort u; _Float16 f; } cv;
        cv.u = v.x; tile[nl][c * 4 + 0] = (float)cv.f;
        cv.u = v.y; tile[nl][c * 4 + 1] = (float)cv.f;
        cv.u = v.z; tile[nl][c * 4 + 2] = (float)cv.f;
        cv.u = v.w; tile[nl][c * 4 + 3] = (float)cv.f;
    }
    __syncthreads();
    #pragma unroll
    for (int rr = 0; rr < 4; ++rr) {
        const int ml = r + rr * 16;
        ushort4 hh;
        union { _Float16 f; ushort u; } cv;
        cv.f = (_Float16)tile[c * 4 + 0][ml]; hh.x = cv.u;
        cv.f = (_Float16)tile[c * 4 + 1][ml]; hh.y = cv.u;
        cv.f = (_Float16)tile[c * 4 + 2][ml]; hh.z = cv.u;
        cv.f = (_Float16)tile[c * 4 + 3][ml]; hh.w = cv.u;
        *(ushort4*)(oth + (size_t)(m0 + ml) * HIDDEN + n0 + c * 4) = hh;
    }
}

// ---------------------------------------------------------------------------
// Output GEMM (r20/r22/r24-VALIDATED, byte-identical)
// ---------------------------------------------------------------------------
__global__ __launch_bounds__(1024, 1) void gemm_out_mfma8(
    const ushort* __restrict__ oth, const ushort* __restrict__ woh,
    const float* __restrict__ bo, float* __restrict__ out)
{
    __shared__ ushort Ah[3][8192];
    __shared__ ushort Bh[3][8192];

    const int tid  = threadIdx.x;
    const int lane = tid & 63;
    const int wid  = tid >> 6;
    const int wr   = wid >> 2;
    const int wc   = wid & 3;
    const int m0   = blockIdx.x * 256;
    const int n0   = blockIdx.y * 256;

    const int row = tid >> 2;
    const int chS = (tid & 3) ^ ((row >> 1) & 3);

    const int fr = lane & 15;
    const int fc = lane >> 4;
    const int cc = (fc ^ ((fr >> 1) & 3)) * 8;

    f32x4 acc[4][4];
    #pragma unroll
    for (int rf = 0; rf < 4; ++rf)
        #pragma unroll
        for (int cf = 0; cf < 4; ++cf)
            acc[rf][cf] = (f32x4){0.f, 0.f, 0.f, 0.f};

#if HAVE_GLL
    #define OUT_STAGE(K0, SLOT) {                                                  \
        const size_t ga = (size_t)(m0 + row) * HIDDEN + (K0) + (size_t)chS * 8;    \
        const size_t gb = (size_t)(n0 + row) * HIDDEN + (K0) + (size_t)chS * 8;    \
        gload16(oth + ga, &Ah[SLOT][(size_t)tid * 8]);                             \
        gload16(woh + gb, &Bh[SLOT][(size_t)tid * 8]);                             \
    }
#else
    #define OUT_STAGE(K0, SLOT) {                                                  \
        const size_t ga = (size_t)(m0 + row) * HIDDEN + (K0) + (size_t)chS * 8;    \
        const size_t gb = (size_t)(n0 + row) * HIDDEN + (K0) + (size_t)chS * 8;    \
        *(f16x8*)&Ah[SLOT][(size_t)tid * 8] = *(const f16x8*)(oth + ga);           \
        *(f16x8*)&Bh[SLOT][(size_t)tid * 8] = *(const f16x8*)(woh + gb);           \
    }
#endif

    OUT_STAGE(0, 0);
    OUT_STAGE(32, 1);

    for (int ks = 0; ks < 32; ++ks) {
        const int slot = ks % 3;
#if HAVE_GLL
        if (ks == 31) { asm volatile("s_waitcnt vmcnt(0)" ::: "memory"); }
        else          { asm volatile("s_waitcnt vmcnt(2)" ::: "memory"); }
        __builtin_amdgcn_s_barrier();
        asm volatile("" ::: "memory");
#else
        __syncthreads();
#endif
        {
            const ushort* pAh = Ah[slot];
            const ushort* pBh = Bh[slot];
            f16x8 a_h[4], b_h[4];
            #pragma unroll
            for (int rf = 0; rf < 4; ++rf) {
                const int R = wr * 64 + rf * 16 + fr;
                a_h[rf] = *(const f16x8*)(pAh + R * 32 + cc);
            }
            #pragma unroll
            for (int cf = 0; cf < 4; ++cf) {
                const int R = wc * 64 + cf * 16 + fr;
                b_h[cf] = *(const f16x8*)(pBh + R * 32 + cc);
            }
            #pragma unroll
            for (int rf = 0; rf < 4; ++rf)
                #pragma unroll
                for (int cf = 0; cf < 4; ++cf)
                    acc[rf][cf] = __builtin_amdgcn_mfma_f32_16x16x32_f16(a_h[rf], b_h[cf], acc[rf][cf], 0, 0, 0);
        }
        if (ks + 2 < 32) { OUT_STAGE((ks + 2) * 32, (ks + 2) % 3); }
#if !HAVE_GLL
        __syncthreads();
#endif
    }
    #undef OUT_STAGE

    const int rq = lane >> 4;
    float bo_v[4];
    #pragma unroll
    for (int cf = 0; cf < 4; ++cf) bo_v[cf] = bo[n0 + wc * 64 + cf * 16 + fr];
    #pragma unroll
    for (int rf = 0; rf < 4; ++rf) {
        #pragma unroll
        for (int r = 0; r < 4; ++r) {
            const int ml = wr * 64 + rf * 16 + rq * 4 + r;
            float* dst = out + (size_t)(m0 + ml) * HIDDEN + n0 + wc * 64;
            #pragma unroll
            for (int cf = 0; cf < 4; ++cf)
                dst[cf * 16 + fr] = acc[rf][cf][r] + bo_v[cf];
        }
    }
}

// ---------------------------------------------------------------------------
// Buffers (ws = proven 201.3 MB; peak use 136.3 MB):
//   ws[0..100.66M):        qkvt fp16 [3][1024][16384]
//   ws[100.66..134.2M):    ot16 fp16 [1024][16384]
//   ws[134.2..136.3M):     woh fp16 [1024][1024]
//   After fft: oth (33.5 MB) aliases the dead qkvt region.
//   d_out stash: xh 33.55 + wh 6.29 = 39.8 MB < 67.1; dead before gemm_out.
// ---------------------------------------------------------------------------
extern "C" void kernel_launch(void* const* d_in, const int* in_sizes, int n_in,
                              void* d_out, int out_size, void* d_ws, size_t ws_size,
                              hipStream_t stream)
{
    const float* x  = (const float*)d_in[0];
    const float* Wq = (const float*)d_in[1];
    const float* bq = (const float*)d_in[2];
    const float* Wk = (const float*)d_in[3];
    const float* bk = (const float*)d_in[4];
    const float* Wv = (const float*)d_in[5];
    const float* bv = (const float*)d_in[6];
    const float* Wo = (const float*)d_in[7];
    const float* bo = (const float*)d_in[8];
    float* out = (float*)d_out;

    const size_t plane = (size_t)HIDDEN * M_TOTAL;   // 16.78M elements
    ushort* qkvt = (ushort*)d_ws;                    // fp16 [3][1024][16384]
    ushort* qt16 = qkvt;
    ushort* kt16 = qkvt + plane;
    ushort* vt16 = qkvt + 2 * plane;
    ushort* ot16 = qkvt + 3 * plane;                 // fp16 [1024][16384]
    ushort* woh  = ot16 + plane;                     // fp16 [1024][1024]

    // post-fft stash aliases dead qkvt region
    ushort* oth = qkvt;                              // [16384][1024] fp16

    // fp16 operand stash in d_out (dead before gemm_out writes d_out)
    ushort* xh  = (ushort*)d_out;                    // [16384][1024]
    ushort* wh  = xh + plane;                        // stacked [3072][1024]

    // pre-passes
    cvt16_kernel<<<(unsigned)(plane / 2048), 256, 0, stream>>>(x, xh);
    cvtW_kernel<<<dim3((unsigned)(WSZ / 2048), 4), 256, 0, stream>>>(
        Wq, Wk, Wv, Wo, wh, woh);

    // QKV projections
    gemm_qkv_mfma8<<<dim3(M_TOTAL / 256, 12), 1024, 0, stream>>>(
        xh, wh, bq, bk, bv, qkvt);

    // FFT attention: 2 seqs/block, 48 KiB LDS, fused pointwise+inv-A
    fft_attn_kernel6<<<dim3(HIDDEN * BATCH / 2), 256, 0, stream>>>(
        qt16, kt16, vt16, ot16);

    // transpose ot16 -> oth [m][k]
    transpose_cvt_kernel<<<dim3(M_TOTAL / 64, HIDDEN / 64), 256, 0, stream>>>(
        ot16, oth);

    // output projection
    gemm_out_mfma8<<<dim3(M_TOTAL / 256, HIDDEN / 256), 1024, 0, stream>>>(
        oth, woh, bo, out);
}